// Round 2
// baseline (604.202 us; speedup 1.0000x reference)
//
#include <hip/hip_runtime.h>

#define FC 32768
#define FF 131072
#define LRELU_SLOPE 0.2f
#define ACT_GAIN 1.4142135623730951f
#define CLAMP_V 256.0f

typedef __bf16 bf16x8 __attribute__((ext_vector_type(8)));
typedef float f32x4 __attribute__((ext_vector_type(4)));
typedef float f32x2 __attribute__((ext_vector_type(2)));
typedef unsigned u32x4 __attribute__((ext_vector_type(4)));
typedef unsigned u32x2 __attribute__((ext_vector_type(2)));
typedef unsigned short u16x4 __attribute__((ext_vector_type(4)));

static __device__ __forceinline__ unsigned short f2bf(float f) {
    unsigned u = __float_as_uint(f);
    u += 0x7FFFu + ((u >> 16) & 1u);
    return (unsigned short)(u >> 16);
}
static __device__ __forceinline__ unsigned packbf(float a, float b) {
    return (unsigned)f2bf(a) | ((unsigned)f2bf(b) << 16);
}
static __device__ __forceinline__ float bf2f(unsigned short u) {
    return __uint_as_float(((unsigned)u) << 16);
}
static __device__ __forceinline__ float actf(float v) {
    v = (v < 0.f) ? v * LRELU_SLOPE : v;
    v *= ACT_GAIN;
    return fminf(fmaxf(v, -CLAMP_V), CLAMP_V);
}

// ---------------- styles: wave-per-output affine + zrow init ----------------
__global__ void k_prep2(const float* __restrict__ wsvec,
                        const float* __restrict__ a0w, const float* __restrict__ a0b,
                        const float* __restrict__ a1w, const float* __restrict__ a1b,
                        const float* __restrict__ a2w, const float* __restrict__ a2b,
                        float* __restrict__ s0, float* __restrict__ s1, float* __restrict__ s2,
                        unsigned* __restrict__ zrow)
{
    int lane = threadIdx.x & 63;
    int t = blockIdx.x * 4 + (threadIdx.x >> 6);
    if (t >= 352) {
        if (t == 352) zrow[lane] = 0u;
        return;
    }
    int level, o;
    const float *W, *bptr; float* out;
    if (t < 128)       { level = 0; o = t;       W = a0w; bptr = a0b; out = s0; }
    else if (t < 256)  { level = 1; o = t - 128; W = a1w; bptr = a1b; out = s1; }
    else               { level = 2; o = t - 256; W = a2w; bptr = a2b; out = s2; }
    const float* wrow = wsvec + level * 512;
    const float* Wr = W + (size_t)o * 512;
    f32x4 wa = *(const f32x4*)(wrow + lane * 8);
    f32x4 wb = *(const f32x4*)(wrow + lane * 8 + 4);
    f32x4 va = *(const f32x4*)(Wr + lane * 8);
    f32x4 vb = *(const f32x4*)(Wr + lane * 8 + 4);
    float acc = wa.x * va.x + wa.y * va.y + wa.z * va.z + wa.w * va.w
              + wb.x * vb.x + wb.y * vb.y + wb.z * vb.z + wb.w * vb.w;
    #pragma unroll
    for (int off = 32; off; off >>= 1) acc += __shfl_down(acc, off, 64);
    if (lane == 0) {
        float v = acc * 0.04419417382415922f + bptr[o];
        if (level == 2) v *= 0.10206207261596577f;  // 1/sqrt(96) torgb weight gain
        out[o] = v;
    }
}

// ---------------- fused: cvt (concat->bf16) + composed index ----------------
__global__ void k_misc(const float* __restrict__ x, const float* __restrict__ sf,
                       u16x4* __restrict__ xcat,
                       const int* __restrict__ fn1, const int* __restrict__ pmap,
                       int* __restrict__ cidx)
{
    int b = blockIdx.x;
    if (b < FC * 32 / 256) {
        int gid = b * 256 + threadIdx.x;
        int f = gid >> 5;
        int c4 = (gid & 31) * 4;
        f32x4 v;
        if (c4 < 96) v = *(const f32x4*)(x + (size_t)f * 96 + c4);
        else         v = *(const f32x4*)(sf + (size_t)f * 32 + (c4 - 96));
        u16x4 o;
        o.x = f2bf(v.x); o.y = f2bf(v.y); o.z = f2bf(v.z); o.w = f2bf(v.w);
        __builtin_nontemporal_store(o, &xcat[gid]);
    } else {
        int gid = (b - FC * 32 / 256) * 256 + threadIdx.x;  // FF*9
        int g = fn1[gid];
        cidx[gid] = ((unsigned)g < FF) ? pmap[g] : -1;
    }
}

// ---------------- fused weight prep ----------------
__global__ void k_wmod(const float* __restrict__ wc0, const float* __restrict__ wsd0,
                       const float* __restrict__ wcr0, const float* __restrict__ s0,
                       unsigned short* __restrict__ wm0,
                       const float* __restrict__ wc1, const float* __restrict__ wsd1,
                       const float* __restrict__ wcr1, const float* __restrict__ s1,
                       unsigned short* __restrict__ wm1,
                       const float* __restrict__ wrgb, const float* __restrict__ s2,
                       float* __restrict__ wrgbmod)
{
    int b = blockIdx.x;
    int i = threadIdx.x;  // 128
    if (b == 224) {
        for (int t = i; t < 288; t += 128) {
            int c = t / 96, k = t % 96;
            wrgbmod[c * 96 + k] = wrgb[c * 96 + k] * s2[k];
        }
        return;
    }
    const float *wc, *wsd, *wcr, *s; unsigned short* out; int o, O;
    if (b < 128) { wc = wc0; wsd = wsd0; wcr = wcr0; s = s0; out = wm0; o = b; O = 128; }
    else         { wc = wc1; wsd = wsd1; wcr = wcr1; s = s1; out = wm1; o = b - 128; O = 96; }
    float sv = s[i];
    float pc = wc[o * 128 + i] * sv;
    float ps = wsd[o * 128 + i] * sv;
    float pr = wcr[o * 128 + i] * sv;
    float part = pc * pc + 4.f * ps * ps + 4.f * pr * pr;
    __shared__ float red[2];
    #pragma unroll
    for (int off = 32; off; off >>= 1) part += __shfl_down(part, off, 64);
    if ((threadIdx.x & 63) == 0) red[threadIdx.x >> 6] = part;
    __syncthreads();
    float d = rsqrtf(red[0] + red[1] + 1e-8f);
    out[(0 * O + o) * 128 + i] = f2bf(pc * d);
    out[(1 * O + o) * 128 + i] = f2bf(ps * d);
    out[(2 * O + o) * 128 + i] = f2bf(pr * d);
}

// ---------------- FUSED gemm0 + gather0 ----------------
// hc0[g][128] = max_{j=0..8} W_{t(j)} . xcat[fn0[g,j]]  (OOB neighbor -> zero row)
// One wave = 16 faces x 128 output channels. ~90 live VGPRs -> no spill at cap 128.
__launch_bounds__(256, 4)
__global__ void k_fgemm0(const unsigned short* __restrict__ xcat,
                         const unsigned short* __restrict__ wm,
                         const int* __restrict__ fn0,
                         const unsigned* __restrict__ zrow,
                         unsigned* __restrict__ hc0)
{
    int lane = threadIdx.x & 63;
    int w = threadIdx.x >> 6;
    int fbase = (blockIdx.x * 4 + w) * 16;
    int quad = lane >> 4, l15 = lane & 15;
    int face = fbase + l15;
    const char* hb = (const char*)xcat;
    const char* wb = (const char*)wm;

    int id[9];
    #pragma unroll
    for (int j = 0; j < 9; ++j) id[j] = fn0[(size_t)face * 9 + j];

    f32x4 ymax[8];
    #pragma unroll
    for (int mt = 0; mt < 8; ++mt)
        #pragma unroll
        for (int r = 0; r < 4; ++r) ymax[mt][r] = -3.0e38f;

    #pragma unroll
    for (int j = 0; j < 9; ++j) {
        const int t = (j == 0) ? 0 : ((j < 5) ? 1 : 2);
        const char* src = ((unsigned)id[j] < FC) ? (hb + (size_t)id[j] * 256) : (const char*)zrow;
        bf16x8 bfr[4];
        #pragma unroll
        for (int s = 0; s < 4; ++s)
            bfr[s] = *(const bf16x8*)(src + s * 64 + quad * 16);
        f32x4 acc[8];
        #pragma unroll
        for (int mt = 0; mt < 8; ++mt)
            #pragma unroll
            for (int r = 0; r < 4; ++r) acc[mt][r] = 0.f;
        #pragma unroll
        for (int s = 0; s < 4; ++s) {
            #pragma unroll
            for (int mt = 0; mt < 8; ++mt) {
                bf16x8 afr = *(const bf16x8*)(wb + (size_t)(((t * 128 + mt * 16 + l15) * 128 + s * 32 + quad * 8) * 2));
                acc[mt] = __builtin_amdgcn_mfma_f32_16x16x32_bf16(afr, bfr[s], acc[mt], 0, 0, 0);
            }
        }
        #pragma unroll
        for (int mt = 0; mt < 8; ++mt)
            #pragma unroll
            for (int r = 0; r < 4; ++r)
                ymax[mt][r] = fmaxf(ymax[mt][r], acc[mt][r]);
    }

    #pragma unroll
    for (int mt = 0; mt < 8; ++mt) {
        u32x2 v;
        v.x = packbf(ymax[mt][0], ymax[mt][1]);
        v.y = packbf(ymax[mt][2], ymax[mt][3]);
        __builtin_nontemporal_store(v, (u32x2*)(hc0 + (size_t)face * 64 + mt * 8 + quad * 2));
    }
}

// ---------------- upsample + noise + act -> h1 bf16 [FF][128] ----------------
__global__ void k_upsample(const unsigned* __restrict__ hc, const int* __restrict__ cidx,
                           const float* __restrict__ nco0,
                           const float* __restrict__ ns0p, const float* __restrict__ bias0,
                           unsigned* __restrict__ h1u, const unsigned* __restrict__ zrow)
{
    int gid = blockIdx.x * 256 + threadIdx.x;  // FF*16
    int f = gid >> 4;
    int c = gid & 15;
    int id[9];
    #pragma unroll
    for (int j = 0; j < 9; ++j) id[j] = cidx[f * 9 + j];
    u32x4 v[9];
    #pragma unroll
    for (int j = 0; j < 9; ++j) {
        const unsigned* p = (id[j] >= 0) ? (hc + (size_t)id[j] * 64) : zrow;
        v[j] = *(const u32x4*)(p + c * 4);
    }
    float nz = nco0[f] * ns0p[0];
    f32x4 b0 = *(const f32x4*)(bias0 + c * 8);
    f32x4 b1 = *(const f32x4*)(bias0 + c * 8 + 4);
    const float inv9 = 1.f / 9.f;
    u32x4 out;
    #pragma unroll
    for (int k = 0; k < 4; ++k) {
        float a0 = 0.f, a1 = 0.f;
        #pragma unroll
        for (int j = 0; j < 9; ++j) {
            a0 += bf2f((unsigned short)v[j][k]);
            a1 += bf2f((unsigned short)(v[j][k] >> 16));
        }
        float bb0 = (k < 2) ? ((k == 0) ? b0.x : b0.z) : ((k == 2) ? b1.x : b1.z);
        float bb1 = (k < 2) ? ((k == 0) ? b0.y : b0.w) : ((k == 2) ? b1.y : b1.w);
        a0 = actf(a0 * inv9 + nz + bb0);
        a1 = actf(a1 * inv9 + nz + bb1);
        out[k] = packbf(a0, a1);
    }
    __builtin_nontemporal_store(out, (u32x4*)(h1u + (size_t)f * 64 + c * 4));
}

// ---------------- FUSED gemm1 + gather1 + act + rgb dot ----------------
// One wave = 16 faces x 96 output channels. Live data ~73 VGPRs -> no spill at cap 128.
// ymax in f32, then act/bias/noise, f32 out_h store, rgb partial dot + quad shfl reduce.
__launch_bounds__(256, 4)
__global__ void k_fgemm1(const unsigned short* __restrict__ h1,
                         const unsigned short* __restrict__ wm,
                         const int* __restrict__ fn1,
                         const unsigned* __restrict__ zrow,
                         const float* __restrict__ nco1, const float* __restrict__ ns1p,
                         const float* __restrict__ bias1, const float* __restrict__ wrgbmod,
                         float* __restrict__ hout, f32x4* __restrict__ rgb3)
{
    int lane = threadIdx.x & 63;
    int w = threadIdx.x >> 6;
    int fbase = (blockIdx.x * 4 + w) * 16;
    int quad = lane >> 4, l15 = lane & 15;
    int face = fbase + l15;
    const char* hb = (const char*)h1;
    const char* wb = (const char*)wm;

    int id[9];
    #pragma unroll
    for (int j = 0; j < 9; ++j) id[j] = fn1[(size_t)face * 9 + j];

    f32x4 ymax[6];
    #pragma unroll
    for (int mt = 0; mt < 6; ++mt)
        #pragma unroll
        for (int r = 0; r < 4; ++r) ymax[mt][r] = -3.0e38f;

    #pragma unroll
    for (int j = 0; j < 9; ++j) {
        const int t = (j == 0) ? 0 : ((j < 5) ? 1 : 2);
        const char* src = ((unsigned)id[j] < FF) ? (hb + (size_t)id[j] * 256) : (const char*)zrow;
        bf16x8 bfr[4];
        #pragma unroll
        for (int s = 0; s < 4; ++s)
            bfr[s] = *(const bf16x8*)(src + s * 64 + quad * 16);
        f32x4 acc[6];
        #pragma unroll
        for (int mt = 0; mt < 6; ++mt)
            #pragma unroll
            for (int r = 0; r < 4; ++r) acc[mt][r] = 0.f;
        #pragma unroll
        for (int s = 0; s < 4; ++s) {
            #pragma unroll
            for (int mt = 0; mt < 6; ++mt) {
                bf16x8 afr = *(const bf16x8*)(wb + (size_t)(((t * 96 + mt * 16 + l15) * 128 + s * 32 + quad * 8) * 2));
                acc[mt] = __builtin_amdgcn_mfma_f32_16x16x32_bf16(afr, bfr[s], acc[mt], 0, 0, 0);
            }
        }
        #pragma unroll
        for (int mt = 0; mt < 6; ++mt)
            #pragma unroll
            for (int r = 0; r < 4; ++r)
                ymax[mt][r] = fmaxf(ymax[mt][r], acc[mt][r]);
    }

    float ns1 = ns1p[0];
    float nz = nco1[face] * ns1;
    float p0 = 0.f, p1 = 0.f, p2 = 0.f;
    #pragma unroll
    for (int mt = 0; mt < 6; ++mt) {
        f32x4 bv = *(const f32x4*)(bias1 + mt * 16 + quad * 4);
        f32x4 hv;
        #pragma unroll
        for (int r = 0; r < 4; ++r) hv[r] = actf(ymax[mt][r] + nz + bv[r]);
        __builtin_nontemporal_store(hv, (f32x4*)(hout + (size_t)face * 96 + mt * 16 + quad * 4));
        f32x4 w0 = *(const f32x4*)(wrgbmod + mt * 16 + quad * 4);
        f32x4 w1 = *(const f32x4*)(wrgbmod + 96 + mt * 16 + quad * 4);
        f32x4 w2 = *(const f32x4*)(wrgbmod + 192 + mt * 16 + quad * 4);
        p0 += hv.x * w0.x + hv.y * w0.y + hv.z * w0.z + hv.w * w0.w;
        p1 += hv.x * w1.x + hv.y * w1.y + hv.z * w1.z + hv.w * w1.w;
        p2 += hv.x * w2.x + hv.y * w2.y + hv.z * w2.z + hv.w * w2.w;
    }
    p0 += __shfl_xor(p0, 16, 64); p0 += __shfl_xor(p0, 32, 64);
    p1 += __shfl_xor(p1, 16, 64); p1 += __shfl_xor(p1, 32, 64);
    p2 += __shfl_xor(p2, 16, 64); p2 += __shfl_xor(p2, 32, 64);
    if (quad == 0) {
        f32x4 o; o.x = p0; o.y = p1; o.z = p2; o.w = 0.f;
        __builtin_nontemporal_store(o, &rgb3[face]);
    }
}

// ---------------- torgb final: img_out = mean9(img[cidx]) + clamp(rgb3[g0]+b) ----------------
__global__ void k_torgb2(const f32x4* __restrict__ rgb3, const int* __restrict__ fn1,
                         const int* __restrict__ cidx, const float* __restrict__ img,
                         const float* __restrict__ brgb, float* __restrict__ imgout)
{
    int f = blockIdx.x * 256 + threadIdx.x;
    int g0 = fn1[(size_t)f * 9];
    float y0 = 0.f, y1 = 0.f, y2 = 0.f;
    if ((unsigned)g0 < FF) {
        f32x4 y = rgb3[g0];
        y0 = y.x; y1 = y.y; y2 = y.z;
    }
    y0 = fminf(fmaxf(y0 + brgb[0], -CLAMP_V), CLAMP_V);
    y1 = fminf(fmaxf(y1 + brgb[1], -CLAMP_V), CLAMP_V);
    y2 = fminf(fmaxf(y2 + brgb[2], -CLAMP_V), CLAMP_V);
    float i0 = 0.f, i1 = 0.f, i2 = 0.f;
    #pragma unroll
    for (int j = 0; j < 9; ++j) {
        int id = cidx[f * 9 + j];
        if (id >= 0) {
            const float* ir = img + (size_t)id * 3;
            i0 += ir[0]; i1 += ir[1]; i2 += ir[2];
        }
    }
    const float inv9 = 1.f / 9.f;
    imgout[(size_t)f * 3 + 0] = i0 * inv9 + y0;
    imgout[(size_t)f * 3 + 1] = i1 * inv9 + y1;
    imgout[(size_t)f * 3 + 2] = i2 * inv9 + y2;
}

extern "C" void kernel_launch(void* const* d_in, const int* in_sizes, int n_in,
                              void* d_out, int out_size, void* d_ws, size_t ws_size,
                              hipStream_t stream) {
    const float* x     = (const float*)d_in[0];
    const float* sfeat = (const float*)d_in[1];
    const float* img   = (const float*)d_in[2];
    const float* wsv   = (const float*)d_in[3];
    const int* fn0     = (const int*)d_in[4];
    const int* fn1     = (const int*)d_in[5];
    const int* pmap    = (const int*)d_in[6];
    const float* a0w   = (const float*)d_in[9];
    const float* a0b   = (const float*)d_in[10];
    const float* wc0   = (const float*)d_in[11];
    const float* wsd0  = (const float*)d_in[12];
    const float* wcr0  = (const float*)d_in[13];
    const float* ns0   = (const float*)d_in[14];
    const float* bias0 = (const float*)d_in[15];
    const float* nco0  = (const float*)d_in[16];
    const float* a1w   = (const float*)d_in[17];
    const float* a1b   = (const float*)d_in[18];
    const float* wc1   = (const float*)d_in[19];
    const float* wsd1  = (const float*)d_in[20];
    const float* wcr1  = (const float*)d_in[21];
    const float* ns1   = (const float*)d_in[22];
    const float* bias1 = (const float*)d_in[23];
    const float* nco1  = (const float*)d_in[24];
    const float* a2w   = (const float*)d_in[25];
    const float* a2b   = (const float*)d_in[26];
    const float* wrgb  = (const float*)d_in[27];
    const float* brgb  = (const float*)d_in[28];

    char* wsb = (char*)d_ws;
    float* s0            = (float*)(wsb + 0);
    float* s1            = (float*)(wsb + 512);
    float* s2            = (float*)(wsb + 1024);
    float* wrgbmod       = (float*)(wsb + 1536);
    unsigned* zrow       = (unsigned*)(wsb + 4096);
    unsigned short* wm0  = (unsigned short*)(wsb + 8192);
    unsigned short* wm1  = (unsigned short*)(wsb + 8192 + 98304);
    unsigned short* xcat = (unsigned short*)(wsb + 262144);      // 8.39 MB
    unsigned* hc0        = (unsigned*)(wsb + 33816576);          // 8.39 MB
    unsigned short* h1   = (unsigned short*)(wsb + 42205184);    // 33.55 MB
    int* cidx            = (int*)(wsb + 75759616);               // 4.72 MB
    f32x4* rgb3          = (f32x4*)(wsb + 155975680);            // 2.10 MB

    float* out_h   = (float*)d_out;
    float* out_img = out_h + (size_t)FF * 96;

    k_misc<<<FC * 32 / 256 + FF * 9 / 256, 256, 0, stream>>>(x, sfeat, (u16x4*)xcat, fn1, pmap, cidx);
    k_prep2<<<89, 256, 0, stream>>>(wsv, a0w, a0b, a1w, a1b, a2w, a2b, s0, s1, s2, zrow);
    k_wmod<<<225, 128, 0, stream>>>(wc0, wsd0, wcr0, s0, wm0,
                                    wc1, wsd1, wcr1, s1, wm1, wrgb, s2, wrgbmod);
    k_fgemm0<<<FC / 64, 256, 0, stream>>>(xcat, wm0, fn0, zrow, hc0);
    k_upsample<<<FF * 16 / 256, 256, 0, stream>>>(hc0, cidx, nco0, ns0, bias0, (unsigned*)h1, zrow);
    k_fgemm1<<<FF / 64, 256, 0, stream>>>(h1, wm1, fn1, zrow, nco1, ns1, bias1, wrgbmod,
                                          out_h, rgb3);
    k_torgb2<<<FF / 256, 256, 0, stream>>>(rgb3, fn1, cidx, img, brgb, out_img);
}

// Round 3
// 329.335 us; speedup vs baseline: 1.8346x; 1.8346x over previous
//
#include <hip/hip_runtime.h>

#define FC 32768
#define FF 131072
#define LRELU_SLOPE 0.2f
#define ACT_GAIN 1.4142135623730951f
#define CLAMP_V 256.0f

typedef __bf16 bf16x8 __attribute__((ext_vector_type(8)));
typedef float f32x4 __attribute__((ext_vector_type(4)));
typedef float f32x2 __attribute__((ext_vector_type(2)));
typedef unsigned u32x4 __attribute__((ext_vector_type(4)));
typedef unsigned u32x2 __attribute__((ext_vector_type(2)));
typedef unsigned short u16x4 __attribute__((ext_vector_type(4)));

static __device__ __forceinline__ unsigned short f2bf(float f) {
    unsigned u = __float_as_uint(f);
    u += 0x7FFFu + ((u >> 16) & 1u);
    return (unsigned short)(u >> 16);
}
static __device__ __forceinline__ unsigned packbf(float a, float b) {
    return (unsigned)f2bf(a) | ((unsigned)f2bf(b) << 16);
}
static __device__ __forceinline__ float bf2f(unsigned short u) {
    return __uint_as_float(((unsigned)u) << 16);
}
static __device__ __forceinline__ float actf(float v) {
    v = (v < 0.f) ? v * LRELU_SLOPE : v;
    v *= ACT_GAIN;
    return fminf(fmaxf(v, -CLAMP_V), CLAMP_V);
}

// ---------------- styles: wave-per-output affine + zrow init ----------------
__global__ void k_prep2(const float* __restrict__ wsvec,
                        const float* __restrict__ a0w, const float* __restrict__ a0b,
                        const float* __restrict__ a1w, const float* __restrict__ a1b,
                        const float* __restrict__ a2w, const float* __restrict__ a2b,
                        float* __restrict__ s0, float* __restrict__ s1, float* __restrict__ s2,
                        unsigned* __restrict__ zrow)
{
    int lane = threadIdx.x & 63;
    int t = blockIdx.x * 4 + (threadIdx.x >> 6);
    if (t >= 352) {
        if (t == 352) zrow[lane] = 0u;
        return;
    }
    int level, o;
    const float *W, *bptr; float* out;
    if (t < 128)       { level = 0; o = t;       W = a0w; bptr = a0b; out = s0; }
    else if (t < 256)  { level = 1; o = t - 128; W = a1w; bptr = a1b; out = s1; }
    else               { level = 2; o = t - 256; W = a2w; bptr = a2b; out = s2; }
    const float* wrow = wsvec + level * 512;
    const float* Wr = W + (size_t)o * 512;
    f32x4 wa = *(const f32x4*)(wrow + lane * 8);
    f32x4 wb = *(const f32x4*)(wrow + lane * 8 + 4);
    f32x4 va = *(const f32x4*)(Wr + lane * 8);
    f32x4 vb = *(const f32x4*)(Wr + lane * 8 + 4);
    float acc = wa.x * va.x + wa.y * va.y + wa.z * va.z + wa.w * va.w
              + wb.x * vb.x + wb.y * vb.y + wb.z * vb.z + wb.w * vb.w;
    #pragma unroll
    for (int off = 32; off; off >>= 1) acc += __shfl_down(acc, off, 64);
    if (lane == 0) {
        float v = acc * 0.04419417382415922f + bptr[o];
        if (level == 2) v *= 0.10206207261596577f;  // 1/sqrt(96) torgb weight gain
        out[o] = v;
    }
}

// ---------------- fused: cvt (concat->bf16) + composed index ----------------
__global__ void k_misc(const float* __restrict__ x, const float* __restrict__ sf,
                       u16x4* __restrict__ xcat,
                       const int* __restrict__ fn1, const int* __restrict__ pmap,
                       int* __restrict__ cidx)
{
    int b = blockIdx.x;
    if (b < FC * 32 / 256) {
        int gid = b * 256 + threadIdx.x;
        int f = gid >> 5;
        int c4 = (gid & 31) * 4;
        f32x4 v;
        if (c4 < 96) v = *(const f32x4*)(x + (size_t)f * 96 + c4);
        else         v = *(const f32x4*)(sf + (size_t)f * 32 + (c4 - 96));
        u16x4 o;
        o.x = f2bf(v.x); o.y = f2bf(v.y); o.z = f2bf(v.z); o.w = f2bf(v.w);
        xcat[gid] = o;
    } else {
        int gid = (b - FC * 32 / 256) * 256 + threadIdx.x;  // FF*9
        int g = fn1[gid];
        cidx[gid] = ((unsigned)g < FF) ? pmap[g] : -1;
    }
}

// ---------------- fused weight prep ----------------
__global__ void k_wmod(const float* __restrict__ wc0, const float* __restrict__ wsd0,
                       const float* __restrict__ wcr0, const float* __restrict__ s0,
                       unsigned short* __restrict__ wm0,
                       const float* __restrict__ wc1, const float* __restrict__ wsd1,
                       const float* __restrict__ wcr1, const float* __restrict__ s1,
                       unsigned short* __restrict__ wm1,
                       const float* __restrict__ wrgb, const float* __restrict__ s2,
                       float* __restrict__ wrgbmod)
{
    int b = blockIdx.x;
    int i = threadIdx.x;  // 128
    if (b == 224) {
        for (int t = i; t < 288; t += 128) {
            int c = t / 96, k = t % 96;
            wrgbmod[c * 96 + k] = wrgb[c * 96 + k] * s2[k];
        }
        return;
    }
    const float *wc, *wsd, *wcr, *s; unsigned short* out; int o, O;
    if (b < 128) { wc = wc0; wsd = wsd0; wcr = wcr0; s = s0; out = wm0; o = b; O = 128; }
    else         { wc = wc1; wsd = wsd1; wcr = wcr1; s = s1; out = wm1; o = b - 128; O = 96; }
    float sv = s[i];
    float pc = wc[o * 128 + i] * sv;
    float ps = wsd[o * 128 + i] * sv;
    float pr = wcr[o * 128 + i] * sv;
    float part = pc * pc + 4.f * ps * ps + 4.f * pr * pr;
    __shared__ float red[2];
    #pragma unroll
    for (int off = 32; off; off >>= 1) part += __shfl_down(part, off, 64);
    if ((threadIdx.x & 63) == 0) red[threadIdx.x >> 6] = part;
    __syncthreads();
    float d = rsqrtf(red[0] + red[1] + 1e-8f);
    out[(0 * O + o) * 128 + i] = f2bf(pc * d);
    out[(1 * O + o) * 128 + i] = f2bf(ps * d);
    out[(2 * O + o) * 128 + i] = f2bf(pr * d);
}

// ---------------- FUSED gemm0 + gather0 ----------------
// hc0[g][128] = max_{j=0..8} W_{t(j)} . xcat[fn0[g,j]]  (OOB neighbor -> zero row)
// One wave = 16 faces x 128 output channels. Live ~105 VGPR.
// launch_bounds(256,2): empirically hipcc budget = 128 VGPR (round-1 evidence);
// (256,4) caps at 64 and spills catastrophically (round-2 evidence).
__launch_bounds__(256, 2)
__global__ void k_fgemm0(const unsigned short* __restrict__ xcat,
                         const unsigned short* __restrict__ wm,
                         const int* __restrict__ fn0,
                         const unsigned* __restrict__ zrow,
                         unsigned* __restrict__ hc0)
{
    int lane = threadIdx.x & 63;
    int w = threadIdx.x >> 6;
    int fbase = (blockIdx.x * 4 + w) * 16;
    int quad = lane >> 4, l15 = lane & 15;
    int face = fbase + l15;
    const char* hb = (const char*)xcat;
    const char* wb = (const char*)wm;

    int id[9];
    #pragma unroll
    for (int j = 0; j < 9; ++j) id[j] = fn0[(size_t)face * 9 + j];

    f32x4 ymax[8];
    #pragma unroll
    for (int mt = 0; mt < 8; ++mt)
        #pragma unroll
        for (int r = 0; r < 4; ++r) ymax[mt][r] = -3.0e38f;

    #pragma unroll
    for (int j = 0; j < 9; ++j) {
        const int t = (j == 0) ? 0 : ((j < 5) ? 1 : 2);
        const char* src = ((unsigned)id[j] < FC) ? (hb + (size_t)id[j] * 256) : (const char*)zrow;
        bf16x8 bfr[4];
        #pragma unroll
        for (int s = 0; s < 4; ++s)
            bfr[s] = *(const bf16x8*)(src + s * 64 + quad * 16);
        f32x4 acc[8];
        #pragma unroll
        for (int mt = 0; mt < 8; ++mt)
            #pragma unroll
            for (int r = 0; r < 4; ++r) acc[mt][r] = 0.f;
        #pragma unroll
        for (int s = 0; s < 4; ++s) {
            #pragma unroll
            for (int mt = 0; mt < 8; ++mt) {
                bf16x8 afr = *(const bf16x8*)(wb + (size_t)(((t * 128 + mt * 16 + l15) * 128 + s * 32 + quad * 8) * 2));
                acc[mt] = __builtin_amdgcn_mfma_f32_16x16x32_bf16(afr, bfr[s], acc[mt], 0, 0, 0);
            }
        }
        #pragma unroll
        for (int mt = 0; mt < 8; ++mt)
            #pragma unroll
            for (int r = 0; r < 4; ++r)
                ymax[mt][r] = fmaxf(ymax[mt][r], acc[mt][r]);
    }

    #pragma unroll
    for (int mt = 0; mt < 8; ++mt) {
        u32x2 v;
        v.x = packbf(ymax[mt][0], ymax[mt][1]);
        v.y = packbf(ymax[mt][2], ymax[mt][3]);
        *(u32x2*)(hc0 + (size_t)face * 64 + mt * 8 + quad * 2) = v;
    }
}

// ---------------- upsample + noise + act -> h1 bf16 [FF][128] ----------------
__global__ void k_upsample(const unsigned* __restrict__ hc, const int* __restrict__ cidx,
                           const float* __restrict__ nco0,
                           const float* __restrict__ ns0p, const float* __restrict__ bias0,
                           unsigned* __restrict__ h1u, const unsigned* __restrict__ zrow)
{
    int gid = blockIdx.x * 256 + threadIdx.x;  // FF*16
    int f = gid >> 4;
    int c = gid & 15;
    int id[9];
    #pragma unroll
    for (int j = 0; j < 9; ++j) id[j] = cidx[f * 9 + j];
    u32x4 v[9];
    #pragma unroll
    for (int j = 0; j < 9; ++j) {
        const unsigned* p = (id[j] >= 0) ? (hc + (size_t)id[j] * 64) : zrow;
        v[j] = *(const u32x4*)(p + c * 4);
    }
    float nz = nco0[f] * ns0p[0];
    f32x4 b0 = *(const f32x4*)(bias0 + c * 8);
    f32x4 b1 = *(const f32x4*)(bias0 + c * 8 + 4);
    const float inv9 = 1.f / 9.f;
    u32x4 out;
    #pragma unroll
    for (int k = 0; k < 4; ++k) {
        float a0 = 0.f, a1 = 0.f;
        #pragma unroll
        for (int j = 0; j < 9; ++j) {
            a0 += bf2f((unsigned short)v[j][k]);
            a1 += bf2f((unsigned short)(v[j][k] >> 16));
        }
        float bb0 = (k < 2) ? ((k == 0) ? b0.x : b0.z) : ((k == 2) ? b1.x : b1.z);
        float bb1 = (k < 2) ? ((k == 0) ? b0.y : b0.w) : ((k == 2) ? b1.y : b1.w);
        a0 = actf(a0 * inv9 + nz + bb0);
        a1 = actf(a1 * inv9 + nz + bb1);
        out[k] = packbf(a0, a1);
    }
    *(u32x4*)(h1u + (size_t)f * 64 + c * 4) = out;
}

// ---------------- FUSED gemm1 + gather1 + act + rgb dot ----------------
// One wave = 16 faces x 96 output channels. Live ~100 VGPR -> fits 128 budget of (256,2).
__launch_bounds__(256, 2)
__global__ void k_fgemm1(const unsigned short* __restrict__ h1,
                         const unsigned short* __restrict__ wm,
                         const int* __restrict__ fn1,
                         const unsigned* __restrict__ zrow,
                         const float* __restrict__ nco1, const float* __restrict__ ns1p,
                         const float* __restrict__ bias1, const float* __restrict__ wrgbmod,
                         float* __restrict__ hout, f32x4* __restrict__ rgb3)
{
    int lane = threadIdx.x & 63;
    int w = threadIdx.x >> 6;
    int fbase = (blockIdx.x * 4 + w) * 16;
    int quad = lane >> 4, l15 = lane & 15;
    int face = fbase + l15;
    const char* hb = (const char*)h1;
    const char* wb = (const char*)wm;

    int id[9];
    #pragma unroll
    for (int j = 0; j < 9; ++j) id[j] = fn1[(size_t)face * 9 + j];

    f32x4 ymax[6];
    #pragma unroll
    for (int mt = 0; mt < 6; ++mt)
        #pragma unroll
        for (int r = 0; r < 4; ++r) ymax[mt][r] = -3.0e38f;

    #pragma unroll
    for (int j = 0; j < 9; ++j) {
        const int t = (j == 0) ? 0 : ((j < 5) ? 1 : 2);
        const char* src = ((unsigned)id[j] < FF) ? (hb + (size_t)id[j] * 256) : (const char*)zrow;
        bf16x8 bfr[4];
        #pragma unroll
        for (int s = 0; s < 4; ++s)
            bfr[s] = *(const bf16x8*)(src + s * 64 + quad * 16);
        f32x4 acc[6];
        #pragma unroll
        for (int mt = 0; mt < 6; ++mt)
            #pragma unroll
            for (int r = 0; r < 4; ++r) acc[mt][r] = 0.f;
        #pragma unroll
        for (int s = 0; s < 4; ++s) {
            #pragma unroll
            for (int mt = 0; mt < 6; ++mt) {
                bf16x8 afr = *(const bf16x8*)(wb + (size_t)(((t * 96 + mt * 16 + l15) * 128 + s * 32 + quad * 8) * 2));
                acc[mt] = __builtin_amdgcn_mfma_f32_16x16x32_bf16(afr, bfr[s], acc[mt], 0, 0, 0);
            }
        }
        #pragma unroll
        for (int mt = 0; mt < 6; ++mt)
            #pragma unroll
            for (int r = 0; r < 4; ++r)
                ymax[mt][r] = fmaxf(ymax[mt][r], acc[mt][r]);
    }

    float ns1 = ns1p[0];
    float nz = nco1[face] * ns1;
    float p0 = 0.f, p1 = 0.f, p2 = 0.f;
    #pragma unroll
    for (int mt = 0; mt < 6; ++mt) {
        f32x4 bv = *(const f32x4*)(bias1 + mt * 16 + quad * 4);
        f32x4 hv;
        #pragma unroll
        for (int r = 0; r < 4; ++r) hv[r] = actf(ymax[mt][r] + nz + bv[r]);
        __builtin_nontemporal_store(hv, (f32x4*)(hout + (size_t)face * 96 + mt * 16 + quad * 4));
        f32x4 w0 = *(const f32x4*)(wrgbmod + mt * 16 + quad * 4);
        f32x4 w1 = *(const f32x4*)(wrgbmod + 96 + mt * 16 + quad * 4);
        f32x4 w2 = *(const f32x4*)(wrgbmod + 192 + mt * 16 + quad * 4);
        p0 += hv.x * w0.x + hv.y * w0.y + hv.z * w0.z + hv.w * w0.w;
        p1 += hv.x * w1.x + hv.y * w1.y + hv.z * w1.z + hv.w * w1.w;
        p2 += hv.x * w2.x + hv.y * w2.y + hv.z * w2.z + hv.w * w2.w;
    }
    p0 += __shfl_xor(p0, 16, 64); p0 += __shfl_xor(p0, 32, 64);
    p1 += __shfl_xor(p1, 16, 64); p1 += __shfl_xor(p1, 32, 64);
    p2 += __shfl_xor(p2, 16, 64); p2 += __shfl_xor(p2, 32, 64);
    if (quad == 0) {
        f32x4 o; o.x = p0; o.y = p1; o.z = p2; o.w = 0.f;
        rgb3[face] = o;
    }
}

// ---------------- torgb final: img_out = mean9(img[cidx]) + clamp(rgb3[g0]+b) ----------------
__global__ void k_torgb2(const f32x4* __restrict__ rgb3, const int* __restrict__ fn1,
                         const int* __restrict__ cidx, const float* __restrict__ img,
                         const float* __restrict__ brgb, float* __restrict__ imgout)
{
    int f = blockIdx.x * 256 + threadIdx.x;
    int g0 = fn1[(size_t)f * 9];
    float y0 = 0.f, y1 = 0.f, y2 = 0.f;
    if ((unsigned)g0 < FF) {
        f32x4 y = rgb3[g0];
        y0 = y.x; y1 = y.y; y2 = y.z;
    }
    y0 = fminf(fmaxf(y0 + brgb[0], -CLAMP_V), CLAMP_V);
    y1 = fminf(fmaxf(y1 + brgb[1], -CLAMP_V), CLAMP_V);
    y2 = fminf(fmaxf(y2 + brgb[2], -CLAMP_V), CLAMP_V);
    float i0 = 0.f, i1 = 0.f, i2 = 0.f;
    #pragma unroll
    for (int j = 0; j < 9; ++j) {
        int id = cidx[f * 9 + j];
        if (id >= 0) {
            const float* ir = img + (size_t)id * 3;
            i0 += ir[0]; i1 += ir[1]; i2 += ir[2];
        }
    }
    const float inv9 = 1.f / 9.f;
    imgout[(size_t)f * 3 + 0] = i0 * inv9 + y0;
    imgout[(size_t)f * 3 + 1] = i1 * inv9 + y1;
    imgout[(size_t)f * 3 + 2] = i2 * inv9 + y2;
}

extern "C" void kernel_launch(void* const* d_in, const int* in_sizes, int n_in,
                              void* d_out, int out_size, void* d_ws, size_t ws_size,
                              hipStream_t stream) {
    const float* x     = (const float*)d_in[0];
    const float* sfeat = (const float*)d_in[1];
    const float* img   = (const float*)d_in[2];
    const float* wsv   = (const float*)d_in[3];
    const int* fn0     = (const int*)d_in[4];
    const int* fn1     = (const int*)d_in[5];
    const int* pmap    = (const int*)d_in[6];
    const float* a0w   = (const float*)d_in[9];
    const float* a0b   = (const float*)d_in[10];
    const float* wc0   = (const float*)d_in[11];
    const float* wsd0  = (const float*)d_in[12];
    const float* wcr0  = (const float*)d_in[13];
    const float* ns0   = (const float*)d_in[14];
    const float* bias0 = (const float*)d_in[15];
    const float* nco0  = (const float*)d_in[16];
    const float* a1w   = (const float*)d_in[17];
    const float* a1b   = (const float*)d_in[18];
    const float* wc1   = (const float*)d_in[19];
    const float* wsd1  = (const float*)d_in[20];
    const float* wcr1  = (const float*)d_in[21];
    const float* ns1   = (const float*)d_in[22];
    const float* bias1 = (const float*)d_in[23];
    const float* nco1  = (const float*)d_in[24];
    const float* a2w   = (const float*)d_in[25];
    const float* a2b   = (const float*)d_in[26];
    const float* wrgb  = (const float*)d_in[27];
    const float* brgb  = (const float*)d_in[28];

    char* wsb = (char*)d_ws;
    float* s0            = (float*)(wsb + 0);
    float* s1            = (float*)(wsb + 512);
    float* s2            = (float*)(wsb + 1024);
    float* wrgbmod       = (float*)(wsb + 1536);
    unsigned* zrow       = (unsigned*)(wsb + 4096);
    unsigned short* wm0  = (unsigned short*)(wsb + 8192);
    unsigned short* wm1  = (unsigned short*)(wsb + 8192 + 98304);
    unsigned short* xcat = (unsigned short*)(wsb + 262144);      // 8.39 MB
    unsigned* hc0        = (unsigned*)(wsb + 33816576);          // 8.39 MB
    unsigned short* h1   = (unsigned short*)(wsb + 42205184);    // 33.55 MB
    int* cidx            = (int*)(wsb + 75759616);               // 4.72 MB
    f32x4* rgb3          = (f32x4*)(wsb + 155975680);            // 2.10 MB

    float* out_h   = (float*)d_out;
    float* out_img = out_h + (size_t)FF * 96;

    k_misc<<<FC * 32 / 256 + FF * 9 / 256, 256, 0, stream>>>(x, sfeat, (u16x4*)xcat, fn1, pmap, cidx);
    k_prep2<<<89, 256, 0, stream>>>(wsv, a0w, a0b, a1w, a1b, a2w, a2b, s0, s1, s2, zrow);
    k_wmod<<<225, 128, 0, stream>>>(wc0, wsd0, wcr0, s0, wm0,
                                    wc1, wsd1, wcr1, s1, wm1, wrgb, s2, wrgbmod);
    k_fgemm0<<<FC / 64, 256, 0, stream>>>(xcat, wm0, fn0, zrow, hc0);
    k_upsample<<<FF * 16 / 256, 256, 0, stream>>>(hc0, cidx, nco0, ns0, bias0, (unsigned*)h1, zrow);
    k_fgemm1<<<FF / 64, 256, 0, stream>>>(h1, wm1, fn1, zrow, nco1, ns1, bias1, wrgbmod,
                                          out_h, rgb3);
    k_torgb2<<<FF / 256, 256, 0, stream>>>(rgb3, fn1, cidx, img, brgb, out_img);
}

// Round 4
// 314.050 us; speedup vs baseline: 1.9239x; 1.0487x over previous
//
#include <hip/hip_runtime.h>

#define FC 32768
#define FF 131072
#define LRELU_SLOPE 0.2f
#define ACT_GAIN 1.4142135623730951f
#define CLAMP_V 256.0f

typedef __bf16 bf16x8 __attribute__((ext_vector_type(8)));
typedef float f32x4 __attribute__((ext_vector_type(4)));
typedef float f32x2 __attribute__((ext_vector_type(2)));
typedef unsigned u32x4 __attribute__((ext_vector_type(4)));
typedef unsigned u32x2 __attribute__((ext_vector_type(2)));
typedef unsigned short u16x4 __attribute__((ext_vector_type(4)));

static __device__ __forceinline__ unsigned short f2bf(float f) {
    unsigned u = __float_as_uint(f);
    u += 0x7FFFu + ((u >> 16) & 1u);
    return (unsigned short)(u >> 16);
}
static __device__ __forceinline__ unsigned packbf(float a, float b) {
    return (unsigned)f2bf(a) | ((unsigned)f2bf(b) << 16);
}
static __device__ __forceinline__ float bf2f(unsigned short u) {
    return __uint_as_float(((unsigned)u) << 16);
}
static __device__ __forceinline__ float actf(float v) {
    v = (v < 0.f) ? v * LRELU_SLOPE : v;
    v *= ACT_GAIN;
    return fminf(fmaxf(v, -CLAMP_V), CLAMP_V);
}

// ---------------- styles: wave-per-output affine + zrow init ----------------
__global__ void k_prep2(const float* __restrict__ wsvec,
                        const float* __restrict__ a0w, const float* __restrict__ a0b,
                        const float* __restrict__ a1w, const float* __restrict__ a1b,
                        const float* __restrict__ a2w, const float* __restrict__ a2b,
                        float* __restrict__ s0, float* __restrict__ s1, float* __restrict__ s2,
                        unsigned* __restrict__ zrow)
{
    int lane = threadIdx.x & 63;
    int t = blockIdx.x * 4 + (threadIdx.x >> 6);
    if (t >= 352) {
        if (t == 352) zrow[lane] = 0u;
        return;
    }
    int level, o;
    const float *W, *bptr; float* out;
    if (t < 128)       { level = 0; o = t;       W = a0w; bptr = a0b; out = s0; }
    else if (t < 256)  { level = 1; o = t - 128; W = a1w; bptr = a1b; out = s1; }
    else               { level = 2; o = t - 256; W = a2w; bptr = a2b; out = s2; }
    const float* wrow = wsvec + level * 512;
    const float* Wr = W + (size_t)o * 512;
    f32x4 wa = *(const f32x4*)(wrow + lane * 8);
    f32x4 wb = *(const f32x4*)(wrow + lane * 8 + 4);
    f32x4 va = *(const f32x4*)(Wr + lane * 8);
    f32x4 vb = *(const f32x4*)(Wr + lane * 8 + 4);
    float acc = wa.x * va.x + wa.y * va.y + wa.z * va.z + wa.w * va.w
              + wb.x * vb.x + wb.y * vb.y + wb.z * vb.z + wb.w * vb.w;
    #pragma unroll
    for (int off = 32; off; off >>= 1) acc += __shfl_down(acc, off, 64);
    if (lane == 0) {
        float v = acc * 0.04419417382415922f + bptr[o];
        if (level == 2) v *= 0.10206207261596577f;  // 1/sqrt(96) torgb weight gain
        out[o] = v;
    }
}

// ---------------- fused: cvt (concat->bf16) + composed index ----------------
__global__ void k_misc(const float* __restrict__ x, const float* __restrict__ sf,
                       u16x4* __restrict__ xcat,
                       const int* __restrict__ fn1, const int* __restrict__ pmap,
                       int* __restrict__ cidx)
{
    int b = blockIdx.x;
    if (b < FC * 32 / 256) {
        int gid = b * 256 + threadIdx.x;
        int f = gid >> 5;
        int c4 = (gid & 31) * 4;
        f32x4 v;
        if (c4 < 96) v = *(const f32x4*)(x + (size_t)f * 96 + c4);
        else         v = *(const f32x4*)(sf + (size_t)f * 32 + (c4 - 96));
        u16x4 o;
        o.x = f2bf(v.x); o.y = f2bf(v.y); o.z = f2bf(v.z); o.w = f2bf(v.w);
        xcat[gid] = o;
    } else {
        int gid = (b - FC * 32 / 256) * 256 + threadIdx.x;  // FF*9
        int g = fn1[gid];
        cidx[gid] = ((unsigned)g < FF) ? pmap[g] : -1;
    }
}

// ---------------- fused weight prep ----------------
__global__ void k_wmod(const float* __restrict__ wc0, const float* __restrict__ wsd0,
                       const float* __restrict__ wcr0, const float* __restrict__ s0,
                       unsigned short* __restrict__ wm0,
                       const float* __restrict__ wc1, const float* __restrict__ wsd1,
                       const float* __restrict__ wcr1, const float* __restrict__ s1,
                       unsigned short* __restrict__ wm1,
                       const float* __restrict__ wrgb, const float* __restrict__ s2,
                       float* __restrict__ wrgbmod)
{
    int b = blockIdx.x;
    int i = threadIdx.x;  // 128
    if (b == 224) {
        for (int t = i; t < 288; t += 128) {
            int c = t / 96, k = t % 96;
            wrgbmod[c * 96 + k] = wrgb[c * 96 + k] * s2[k];
        }
        return;
    }
    const float *wc, *wsd, *wcr, *s; unsigned short* out; int o, O;
    if (b < 128) { wc = wc0; wsd = wsd0; wcr = wcr0; s = s0; out = wm0; o = b; O = 128; }
    else         { wc = wc1; wsd = wsd1; wcr = wcr1; s = s1; out = wm1; o = b - 128; O = 96; }
    float sv = s[i];
    float pc = wc[o * 128 + i] * sv;
    float ps = wsd[o * 128 + i] * sv;
    float pr = wcr[o * 128 + i] * sv;
    float part = pc * pc + 4.f * ps * ps + 4.f * pr * pr;
    __shared__ float red[2];
    #pragma unroll
    for (int off = 32; off; off >>= 1) part += __shfl_down(part, off, 64);
    if ((threadIdx.x & 63) == 0) red[threadIdx.x >> 6] = part;
    __syncthreads();
    float d = rsqrtf(red[0] + red[1] + 1e-8f);
    out[(0 * O + o) * 128 + i] = f2bf(pc * d);
    out[(1 * O + o) * 128 + i] = f2bf(ps * d);
    out[(2 * O + o) * 128 + i] = f2bf(pr * d);
}

// ---------------- FUSED gemm0 + gather0, LDS-staged weights ----------------
// hc0[g][128] = max_{j=0..8} W_{t(j)} . xcat[fn0[g,j]]  (OOB neighbor -> zero row)
// One wave = 16 faces x 128 output channels. t=1,2 weight slices (used 4x each)
// staged in 64 KB LDS with XOR-16B swizzle (G4 row-major-128 fix); t=0 (used 1x)
// read from global. launch_bounds(256,2) -> 128 VGPR budget (round-1/2 evidence).
__launch_bounds__(256, 2)
__global__ void k_fgemm0(const unsigned short* __restrict__ xcat,
                         const unsigned short* __restrict__ wm,
                         const int* __restrict__ fn0,
                         const unsigned* __restrict__ zrow,
                         unsigned* __restrict__ hc0)
{
    __shared__ char ldsw[65536];  // rows 0..255 = t=1,2 slices, 256 B/row, swizzled
    int lane = threadIdx.x & 63;
    int w = threadIdx.x >> 6;
    int fbase = (blockIdx.x * 4 + w) * 16;
    int quad = lane >> 4, l15 = lane & 15;
    int face = fbase + l15;
    const char* hb = (const char*)xcat;
    const char* wb = (const char*)wm;

    // stage wm rows 128..383 (t=1,2): chunk i -> row i>>4, col16 (i&15)^(row&7)
    #pragma unroll
    for (int i0 = 0; i0 < 16; ++i0) {
        int i = i0 * 256 + threadIdx.x;
        u32x4 v = *(const u32x4*)(wb + 32768 + (size_t)i * 16);
        int r = i >> 4, c = i & 15;
        *(u32x4*)(ldsw + r * 256 + ((c ^ (r & 7)) * 16)) = v;
    }
    __syncthreads();

    int id[9];
    #pragma unroll
    for (int j = 0; j < 9; ++j) id[j] = fn0[(size_t)face * 9 + j];

    f32x4 ymax[8];
    #pragma unroll
    for (int mt = 0; mt < 8; ++mt)
        #pragma unroll
        for (int r = 0; r < 4; ++r) ymax[mt][r] = -3.0e38f;

    int xr = l15 & 7;  // row&7 for all weight rows this lane touches

    #pragma unroll
    for (int j = 0; j < 9; ++j) {
        const int t = (j == 0) ? 0 : ((j < 5) ? 1 : 2);
        const char* src = ((unsigned)id[j] < FC) ? (hb + (size_t)id[j] * 256) : (const char*)zrow;
        bf16x8 bfr[4];
        #pragma unroll
        for (int s = 0; s < 4; ++s)
            bfr[s] = *(const bf16x8*)(src + s * 64 + quad * 16);
        f32x4 acc[8];
        #pragma unroll
        for (int mt = 0; mt < 8; ++mt)
            #pragma unroll
            for (int r = 0; r < 4; ++r) acc[mt][r] = 0.f;
        #pragma unroll
        for (int s = 0; s < 4; ++s) {
            #pragma unroll
            for (int mt = 0; mt < 8; ++mt) {
                bf16x8 afr;
                if (t == 0)
                    afr = *(const bf16x8*)(wb + (size_t)(((mt * 16 + l15) * 128 + s * 32 + quad * 8) * 2));
                else
                    afr = *(const bf16x8*)(ldsw + ((t - 1) * 128 + mt * 16 + l15) * 256
                                                + (((s * 4 + quad) ^ xr) * 16));
                acc[mt] = __builtin_amdgcn_mfma_f32_16x16x32_bf16(afr, bfr[s], acc[mt], 0, 0, 0);
            }
        }
        #pragma unroll
        for (int mt = 0; mt < 8; ++mt)
            #pragma unroll
            for (int r = 0; r < 4; ++r)
                ymax[mt][r] = fmaxf(ymax[mt][r], acc[mt][r]);
    }

    #pragma unroll
    for (int mt = 0; mt < 8; ++mt) {
        u32x2 v;
        v.x = packbf(ymax[mt][0], ymax[mt][1]);
        v.y = packbf(ymax[mt][2], ymax[mt][3]);
        *(u32x2*)(hc0 + (size_t)face * 64 + mt * 8 + quad * 2) = v;
    }
}

// ---------------- upsample + noise + act -> h1 bf16 [FF][128] ----------------
__global__ void k_upsample(const unsigned* __restrict__ hc, const int* __restrict__ cidx,
                           const float* __restrict__ nco0,
                           const float* __restrict__ ns0p, const float* __restrict__ bias0,
                           unsigned* __restrict__ h1u, const unsigned* __restrict__ zrow)
{
    int gid = blockIdx.x * 256 + threadIdx.x;  // FF*16
    int f = gid >> 4;
    int c = gid & 15;
    int id[9];
    #pragma unroll
    for (int j = 0; j < 9; ++j) id[j] = cidx[f * 9 + j];
    u32x4 v[9];
    #pragma unroll
    for (int j = 0; j < 9; ++j) {
        const unsigned* p = (id[j] >= 0) ? (hc + (size_t)id[j] * 64) : zrow;
        v[j] = *(const u32x4*)(p + c * 4);
    }
    float nz = nco0[f] * ns0p[0];
    f32x4 b0 = *(const f32x4*)(bias0 + c * 8);
    f32x4 b1 = *(const f32x4*)(bias0 + c * 8 + 4);
    const float inv9 = 1.f / 9.f;
    u32x4 out;
    #pragma unroll
    for (int k = 0; k < 4; ++k) {
        float a0 = 0.f, a1 = 0.f;
        #pragma unroll
        for (int j = 0; j < 9; ++j) {
            a0 += bf2f((unsigned short)v[j][k]);
            a1 += bf2f((unsigned short)(v[j][k] >> 16));
        }
        float bb0 = (k < 2) ? ((k == 0) ? b0.x : b0.z) : ((k == 2) ? b1.x : b1.z);
        float bb1 = (k < 2) ? ((k == 0) ? b0.y : b0.w) : ((k == 2) ? b1.y : b1.w);
        a0 = actf(a0 * inv9 + nz + bb0);
        a1 = actf(a1 * inv9 + nz + bb1);
        out[k] = packbf(a0, a1);
    }
    *(u32x4*)(h1u + (size_t)f * 64 + c * 4) = out;
}

// ---------------- FUSED gemm1 + gather1 + act + rgb dot, LDS-staged weights ----
// One wave = 16 faces x 96 output channels. t=1,2 slices (48 KB) in LDS -> 3 blocks/CU.
__launch_bounds__(256, 2)
__global__ void k_fgemm1(const unsigned short* __restrict__ h1,
                         const unsigned short* __restrict__ wm,
                         const int* __restrict__ fn1,
                         const unsigned* __restrict__ zrow,
                         const float* __restrict__ nco1, const float* __restrict__ ns1p,
                         const float* __restrict__ bias1, const float* __restrict__ wrgbmod,
                         float* __restrict__ hout, f32x4* __restrict__ rgb3)
{
    __shared__ char ldsw[49152];  // rows 0..191 = t=1,2 slices, 256 B/row, swizzled
    int lane = threadIdx.x & 63;
    int w = threadIdx.x >> 6;
    int fbase = (blockIdx.x * 4 + w) * 16;
    int quad = lane >> 4, l15 = lane & 15;
    int face = fbase + l15;
    const char* hb = (const char*)h1;
    const char* wb = (const char*)wm;

    // stage wm rows 96..287 (t=1,2)
    #pragma unroll
    for (int i0 = 0; i0 < 12; ++i0) {
        int i = i0 * 256 + threadIdx.x;
        u32x4 v = *(const u32x4*)(wb + 24576 + (size_t)i * 16);
        int r = i >> 4, c = i & 15;
        *(u32x4*)(ldsw + r * 256 + ((c ^ (r & 7)) * 16)) = v;
    }
    __syncthreads();

    int id[9];
    #pragma unroll
    for (int j = 0; j < 9; ++j) id[j] = fn1[(size_t)face * 9 + j];

    f32x4 ymax[6];
    #pragma unroll
    for (int mt = 0; mt < 6; ++mt)
        #pragma unroll
        for (int r = 0; r < 4; ++r) ymax[mt][r] = -3.0e38f;

    int xr = l15 & 7;

    #pragma unroll
    for (int j = 0; j < 9; ++j) {
        const int t = (j == 0) ? 0 : ((j < 5) ? 1 : 2);
        const char* src = ((unsigned)id[j] < FF) ? (hb + (size_t)id[j] * 256) : (const char*)zrow;
        bf16x8 bfr[4];
        #pragma unroll
        for (int s = 0; s < 4; ++s)
            bfr[s] = *(const bf16x8*)(src + s * 64 + quad * 16);
        f32x4 acc[6];
        #pragma unroll
        for (int mt = 0; mt < 6; ++mt)
            #pragma unroll
            for (int r = 0; r < 4; ++r) acc[mt][r] = 0.f;
        #pragma unroll
        for (int s = 0; s < 4; ++s) {
            #pragma unroll
            for (int mt = 0; mt < 6; ++mt) {
                bf16x8 afr;
                if (t == 0)
                    afr = *(const bf16x8*)(wb + (size_t)(((mt * 16 + l15) * 128 + s * 32 + quad * 8) * 2));
                else
                    afr = *(const bf16x8*)(ldsw + ((t - 1) * 96 + mt * 16 + l15) * 256
                                                + (((s * 4 + quad) ^ xr) * 16));
                acc[mt] = __builtin_amdgcn_mfma_f32_16x16x32_bf16(afr, bfr[s], acc[mt], 0, 0, 0);
            }
        }
        #pragma unroll
        for (int mt = 0; mt < 6; ++mt)
            #pragma unroll
            for (int r = 0; r < 4; ++r)
                ymax[mt][r] = fmaxf(ymax[mt][r], acc[mt][r]);
    }

    float ns1 = ns1p[0];
    float nz = nco1[face] * ns1;
    float p0 = 0.f, p1 = 0.f, p2 = 0.f;
    #pragma unroll
    for (int mt = 0; mt < 6; ++mt) {
        f32x4 bv = *(const f32x4*)(bias1 + mt * 16 + quad * 4);
        f32x4 hv;
        #pragma unroll
        for (int r = 0; r < 4; ++r) hv[r] = actf(ymax[mt][r] + nz + bv[r]);
        __builtin_nontemporal_store(hv, (f32x4*)(hout + (size_t)face * 96 + mt * 16 + quad * 4));
        f32x4 w0 = *(const f32x4*)(wrgbmod + mt * 16 + quad * 4);
        f32x4 w1 = *(const f32x4*)(wrgbmod + 96 + mt * 16 + quad * 4);
        f32x4 w2 = *(const f32x4*)(wrgbmod + 192 + mt * 16 + quad * 4);
        p0 += hv.x * w0.x + hv.y * w0.y + hv.z * w0.z + hv.w * w0.w;
        p1 += hv.x * w1.x + hv.y * w1.y + hv.z * w1.z + hv.w * w1.w;
        p2 += hv.x * w2.x + hv.y * w2.y + hv.z * w2.z + hv.w * w2.w;
    }
    p0 += __shfl_xor(p0, 16, 64); p0 += __shfl_xor(p0, 32, 64);
    p1 += __shfl_xor(p1, 16, 64); p1 += __shfl_xor(p1, 32, 64);
    p2 += __shfl_xor(p2, 16, 64); p2 += __shfl_xor(p2, 32, 64);
    if (quad == 0) {
        f32x4 o; o.x = p0; o.y = p1; o.z = p2; o.w = 0.f;
        rgb3[face] = o;
    }
}

// ---------------- torgb final: img_out = mean9(img[cidx]) + clamp(rgb3[g0]+b) ----------------
__global__ void k_torgb2(const f32x4* __restrict__ rgb3, const int* __restrict__ fn1,
                         const int* __restrict__ cidx, const float* __restrict__ img,
                         const float* __restrict__ brgb, float* __restrict__ imgout)
{
    int f = blockIdx.x * 256 + threadIdx.x;
    int g0 = fn1[(size_t)f * 9];
    float y0 = 0.f, y1 = 0.f, y2 = 0.f;
    if ((unsigned)g0 < FF) {
        f32x4 y = rgb3[g0];
        y0 = y.x; y1 = y.y; y2 = y.z;
    }
    y0 = fminf(fmaxf(y0 + brgb[0], -CLAMP_V), CLAMP_V);
    y1 = fminf(fmaxf(y1 + brgb[1], -CLAMP_V), CLAMP_V);
    y2 = fminf(fmaxf(y2 + brgb[2], -CLAMP_V), CLAMP_V);
    float i0 = 0.f, i1 = 0.f, i2 = 0.f;
    #pragma unroll
    for (int j = 0; j < 9; ++j) {
        int id = cidx[f * 9 + j];
        if (id >= 0) {
            const float* ir = img + (size_t)id * 3;
            i0 += ir[0]; i1 += ir[1]; i2 += ir[2];
        }
    }
    const float inv9 = 1.f / 9.f;
    imgout[(size_t)f * 3 + 0] = i0 * inv9 + y0;
    imgout[(size_t)f * 3 + 1] = i1 * inv9 + y1;
    imgout[(size_t)f * 3 + 2] = i2 * inv9 + y2;
}

extern "C" void kernel_launch(void* const* d_in, const int* in_sizes, int n_in,
                              void* d_out, int out_size, void* d_ws, size_t ws_size,
                              hipStream_t stream) {
    const float* x     = (const float*)d_in[0];
    const float* sfeat = (const float*)d_in[1];
    const float* img   = (const float*)d_in[2];
    const float* wsv   = (const float*)d_in[3];
    const int* fn0     = (const int*)d_in[4];
    const int* fn1     = (const int*)d_in[5];
    const int* pmap    = (const int*)d_in[6];
    const float* a0w   = (const float*)d_in[9];
    const float* a0b   = (const float*)d_in[10];
    const float* wc0   = (const float*)d_in[11];
    const float* wsd0  = (const float*)d_in[12];
    const float* wcr0  = (const float*)d_in[13];
    const float* ns0   = (const float*)d_in[14];
    const float* bias0 = (const float*)d_in[15];
    const float* nco0  = (const float*)d_in[16];
    const float* a1w   = (const float*)d_in[17];
    const float* a1b   = (const float*)d_in[18];
    const float* wc1   = (const float*)d_in[19];
    const float* wsd1  = (const float*)d_in[20];
    const float* wcr1  = (const float*)d_in[21];
    const float* ns1   = (const float*)d_in[22];
    const float* bias1 = (const float*)d_in[23];
    const float* nco1  = (const float*)d_in[24];
    const float* a2w   = (const float*)d_in[25];
    const float* a2b   = (const float*)d_in[26];
    const float* wrgb  = (const float*)d_in[27];
    const float* brgb  = (const float*)d_in[28];

    char* wsb = (char*)d_ws;
    float* s0            = (float*)(wsb + 0);
    float* s1            = (float*)(wsb + 512);
    float* s2            = (float*)(wsb + 1024);
    float* wrgbmod       = (float*)(wsb + 1536);
    unsigned* zrow       = (unsigned*)(wsb + 4096);
    unsigned short* wm0  = (unsigned short*)(wsb + 8192);
    unsigned short* wm1  = (unsigned short*)(wsb + 8192 + 98304);
    unsigned short* xcat = (unsigned short*)(wsb + 262144);      // 8.39 MB
    unsigned* hc0        = (unsigned*)(wsb + 33816576);          // 8.39 MB
    unsigned short* h1   = (unsigned short*)(wsb + 42205184);    // 33.55 MB
    int* cidx            = (int*)(wsb + 75759616);               // 4.72 MB
    f32x4* rgb3          = (f32x4*)(wsb + 155975680);            // 2.10 MB

    float* out_h   = (float*)d_out;
    float* out_img = out_h + (size_t)FF * 96;

    k_misc<<<FC * 32 / 256 + FF * 9 / 256, 256, 0, stream>>>(x, sfeat, (u16x4*)xcat, fn1, pmap, cidx);
    k_prep2<<<89, 256, 0, stream>>>(wsv, a0w, a0b, a1w, a1b, a2w, a2b, s0, s1, s2, zrow);
    k_wmod<<<225, 128, 0, stream>>>(wc0, wsd0, wcr0, s0, wm0,
                                    wc1, wsd1, wcr1, s1, wm1, wrgb, s2, wrgbmod);
    k_fgemm0<<<FC / 64, 256, 0, stream>>>(xcat, wm0, fn0, zrow, hc0);
    k_upsample<<<FF * 16 / 256, 256, 0, stream>>>(hc0, cidx, nco0, ns0, bias0, (unsigned*)h1, zrow);
    k_fgemm1<<<FF / 64, 256, 0, stream>>>(h1, wm1, fn1, zrow, nco1, ns1, bias1, wrgbmod,
                                          out_h, rgb3);
    k_torgb2<<<FF / 256, 256, 0, stream>>>(rgb3, fn1, cidx, img, brgb, out_img);
}

// Round 5
// 287.625 us; speedup vs baseline: 2.1007x; 1.0919x over previous
//
#include <hip/hip_runtime.h>

#define FC 32768
#define FF 131072
#define LRELU_SLOPE 0.2f
#define ACT_GAIN 1.4142135623730951f
#define CLAMP_V 256.0f

typedef __bf16 bf16x8 __attribute__((ext_vector_type(8)));
typedef float f32x4 __attribute__((ext_vector_type(4)));
typedef float f32x2 __attribute__((ext_vector_type(2)));
typedef unsigned u32x4 __attribute__((ext_vector_type(4)));
typedef unsigned u32x2 __attribute__((ext_vector_type(2)));
typedef unsigned short u16x4 __attribute__((ext_vector_type(4)));

static __device__ __forceinline__ unsigned short f2bf(float f) {
    unsigned u = __float_as_uint(f);
    u += 0x7FFFu + ((u >> 16) & 1u);
    return (unsigned short)(u >> 16);
}
static __device__ __forceinline__ unsigned packbf(float a, float b) {
    return (unsigned)f2bf(a) | ((unsigned)f2bf(b) << 16);
}
static __device__ __forceinline__ float bf2f(unsigned short u) {
    return __uint_as_float(((unsigned)u) << 16);
}
static __device__ __forceinline__ float actf(float v) {
    v = (v < 0.f) ? v * LRELU_SLOPE : v;
    v *= ACT_GAIN;
    return fminf(fmaxf(v, -CLAMP_V), CLAMP_V);
}
// XCD-aware chunked swizzle; valid when nwg % 8 == 0 (all our grids are).
static __device__ __forceinline__ int xcd_swz(int bid, int nwg) {
    return (bid & 7) * (nwg >> 3) + (bid >> 3);
}

// ---------------- styles: wave-per-output affine + zrow init ----------------
__global__ void k_prep2(const float* __restrict__ wsvec,
                        const float* __restrict__ a0w, const float* __restrict__ a0b,
                        const float* __restrict__ a1w, const float* __restrict__ a1b,
                        const float* __restrict__ a2w, const float* __restrict__ a2b,
                        float* __restrict__ s0, float* __restrict__ s1, float* __restrict__ s2,
                        unsigned* __restrict__ zrow)
{
    int lane = threadIdx.x & 63;
    int t = blockIdx.x * 4 + (threadIdx.x >> 6);
    if (t >= 352) {
        if (t == 352) zrow[lane] = 0u;
        return;
    }
    int level, o;
    const float *W, *bptr; float* out;
    if (t < 128)       { level = 0; o = t;       W = a0w; bptr = a0b; out = s0; }
    else if (t < 256)  { level = 1; o = t - 128; W = a1w; bptr = a1b; out = s1; }
    else               { level = 2; o = t - 256; W = a2w; bptr = a2b; out = s2; }
    const float* wrow = wsvec + level * 512;
    const float* Wr = W + (size_t)o * 512;
    f32x4 wa = *(const f32x4*)(wrow + lane * 8);
    f32x4 wb = *(const f32x4*)(wrow + lane * 8 + 4);
    f32x4 va = *(const f32x4*)(Wr + lane * 8);
    f32x4 vb = *(const f32x4*)(Wr + lane * 8 + 4);
    float acc = wa.x * va.x + wa.y * va.y + wa.z * va.z + wa.w * va.w
              + wb.x * vb.x + wb.y * vb.y + wb.z * vb.z + wb.w * vb.w;
    #pragma unroll
    for (int off = 32; off; off >>= 1) acc += __shfl_down(acc, off, 64);
    if (lane == 0) {
        float v = acc * 0.04419417382415922f + bptr[o];
        if (level == 2) v *= 0.10206207261596577f;  // 1/sqrt(96) torgb weight gain
        out[o] = v;
    }
}

// ---------------- fused: cvt (concat->bf16) + composed index ----------------
__global__ void k_misc(const float* __restrict__ x, const float* __restrict__ sf,
                       u16x4* __restrict__ xcat,
                       const int* __restrict__ fn1, const int* __restrict__ pmap,
                       int* __restrict__ cidx)
{
    int b = blockIdx.x;
    if (b < FC * 32 / 256) {
        int gid = b * 256 + threadIdx.x;
        int f = gid >> 5;
        int c4 = (gid & 31) * 4;
        f32x4 v;
        if (c4 < 96) v = *(const f32x4*)(x + (size_t)f * 96 + c4);
        else         v = *(const f32x4*)(sf + (size_t)f * 32 + (c4 - 96));
        u16x4 o;
        o.x = f2bf(v.x); o.y = f2bf(v.y); o.z = f2bf(v.z); o.w = f2bf(v.w);
        xcat[gid] = o;
    } else {
        int gid = (b - FC * 32 / 256) * 256 + threadIdx.x;  // FF*9
        int g = fn1[gid];
        cidx[gid] = ((unsigned)g < FF) ? pmap[g] : -1;
    }
}

// ---------------- fused weight prep ----------------
__global__ void k_wmod(const float* __restrict__ wc0, const float* __restrict__ wsd0,
                       const float* __restrict__ wcr0, const float* __restrict__ s0,
                       unsigned short* __restrict__ wm0,
                       const float* __restrict__ wc1, const float* __restrict__ wsd1,
                       const float* __restrict__ wcr1, const float* __restrict__ s1,
                       unsigned short* __restrict__ wm1,
                       const float* __restrict__ wrgb, const float* __restrict__ s2,
                       float* __restrict__ wrgbmod)
{
    int b = blockIdx.x;
    int i = threadIdx.x;  // 128
    if (b == 224) {
        for (int t = i; t < 288; t += 128) {
            int c = t / 96, k = t % 96;
            wrgbmod[c * 96 + k] = wrgb[c * 96 + k] * s2[k];
        }
        return;
    }
    const float *wc, *wsd, *wcr, *s; unsigned short* out; int o, O;
    if (b < 128) { wc = wc0; wsd = wsd0; wcr = wcr0; s = s0; out = wm0; o = b; O = 128; }
    else         { wc = wc1; wsd = wsd1; wcr = wcr1; s = s1; out = wm1; o = b - 128; O = 96; }
    float sv = s[i];
    float pc = wc[o * 128 + i] * sv;
    float ps = wsd[o * 128 + i] * sv;
    float pr = wcr[o * 128 + i] * sv;
    float part = pc * pc + 4.f * ps * ps + 4.f * pr * pr;
    __shared__ float red[2];
    #pragma unroll
    for (int off = 32; off; off >>= 1) part += __shfl_down(part, off, 64);
    if ((threadIdx.x & 63) == 0) red[threadIdx.x >> 6] = part;
    __syncthreads();
    float d = rsqrtf(red[0] + red[1] + 1e-8f);
    out[(0 * O + o) * 128 + i] = f2bf(pc * d);
    out[(1 * O + o) * 128 + i] = f2bf(ps * d);
    out[(2 * O + o) * 128 + i] = f2bf(pr * d);
}

// ---------------- FUSED gemm0 + gather0, LDS weights, channel-split waves ----
// hc0[g][128] = max_{j=0..8} W_{t(j)} . xcat[fn0[g,j]]
// Block: 4 waves = 2 face-groups x 2 channel-halves. Each wave: 16 faces x 64 ch
// (4 mt blocks). Live ~75 VGPR -> no spill at 128 budget (round-4 lesson: the
// 8-mt variant + LDS staging spilled: WRITE 105 MB, 122 us).
__launch_bounds__(256, 2)
__global__ void k_fgemm0(const unsigned short* __restrict__ xcat,
                         const unsigned short* __restrict__ wm,
                         const int* __restrict__ fn0,
                         const unsigned* __restrict__ zrow,
                         unsigned* __restrict__ hc0)
{
    __shared__ char ldsw[65536];  // rows 0..255 = t=1,2 slices, 256 B/row, swizzled
    int bid = xcd_swz(blockIdx.x, gridDim.x);
    int lane = threadIdx.x & 63;
    int w = threadIdx.x >> 6;
    int fgrp = w >> 1;
    int mtb = (w & 1) * 4;
    int fbase = (bid * 2 + fgrp) * 16;
    int quad = lane >> 4, l15 = lane & 15;
    int face = fbase + l15;
    const char* hb = (const char*)xcat;
    const char* wb = (const char*)wm;

    // stage wm rows 128..383 (t=1,2): chunk i -> row i>>4, col16 (i&15)^(row&7)
    #pragma unroll
    for (int i0 = 0; i0 < 16; ++i0) {
        int i = i0 * 256 + threadIdx.x;
        u32x4 v = *(const u32x4*)(wb + 32768 + (size_t)i * 16);
        int r = i >> 4, c = i & 15;
        *(u32x4*)(ldsw + r * 256 + ((c ^ (r & 7)) * 16)) = v;
    }
    __syncthreads();

    int id[9];
    #pragma unroll
    for (int j = 0; j < 9; ++j) id[j] = fn0[(size_t)face * 9 + j];

    f32x4 ymax[4];
    #pragma unroll
    for (int mi = 0; mi < 4; ++mi)
        #pragma unroll
        for (int r = 0; r < 4; ++r) ymax[mi][r] = -3.0e38f;

    int xr = l15 & 7;  // row&7 for all weight rows this lane touches

    #pragma unroll
    for (int j = 0; j < 9; ++j) {
        const int t = (j == 0) ? 0 : ((j < 5) ? 1 : 2);
        const char* src = ((unsigned)id[j] < FC) ? (hb + (size_t)id[j] * 256) : (const char*)zrow;
        bf16x8 bfr[4];
        #pragma unroll
        for (int s = 0; s < 4; ++s)
            bfr[s] = *(const bf16x8*)(src + s * 64 + quad * 16);
        f32x4 acc[4];
        #pragma unroll
        for (int mi = 0; mi < 4; ++mi)
            #pragma unroll
            for (int r = 0; r < 4; ++r) acc[mi][r] = 0.f;
        #pragma unroll
        for (int s = 0; s < 4; ++s) {
            #pragma unroll
            for (int mi = 0; mi < 4; ++mi) {
                bf16x8 afr;
                if (t == 0)
                    afr = *(const bf16x8*)(wb + (size_t)((((mtb + mi) * 16 + l15) * 128 + s * 32 + quad * 8) * 2));
                else
                    afr = *(const bf16x8*)(ldsw + ((t - 1) * 128 + (mtb + mi) * 16 + l15) * 256
                                                + (((s * 4 + quad) ^ xr) * 16));
                acc[mi] = __builtin_amdgcn_mfma_f32_16x16x32_bf16(afr, bfr[s], acc[mi], 0, 0, 0);
            }
        }
        #pragma unroll
        for (int mi = 0; mi < 4; ++mi)
            #pragma unroll
            for (int r = 0; r < 4; ++r)
                ymax[mi][r] = fmaxf(ymax[mi][r], acc[mi][r]);
    }

    #pragma unroll
    for (int mi = 0; mi < 4; ++mi) {
        u32x2 v;
        v.x = packbf(ymax[mi][0], ymax[mi][1]);
        v.y = packbf(ymax[mi][2], ymax[mi][3]);
        *(u32x2*)(hc0 + (size_t)face * 64 + (mtb + mi) * 8 + quad * 2) = v;
    }
}

// ---------------- upsample + noise + act -> h1 bf16 [FF][128] ----------------
__global__ void k_upsample(const unsigned* __restrict__ hc, const int* __restrict__ cidx,
                           const float* __restrict__ nco0,
                           const float* __restrict__ ns0p, const float* __restrict__ bias0,
                           unsigned* __restrict__ h1u, const unsigned* __restrict__ zrow)
{
    int bid = xcd_swz(blockIdx.x, gridDim.x);
    int gid = bid * 256 + threadIdx.x;  // FF*16
    int f = gid >> 4;
    int c = gid & 15;
    int id[9];
    #pragma unroll
    for (int j = 0; j < 9; ++j) id[j] = cidx[f * 9 + j];
    u32x4 v[9];
    #pragma unroll
    for (int j = 0; j < 9; ++j) {
        const unsigned* p = (id[j] >= 0) ? (hc + (size_t)id[j] * 64) : zrow;
        v[j] = *(const u32x4*)(p + c * 4);
    }
    float nz = nco0[f] * ns0p[0];
    f32x4 b0 = *(const f32x4*)(bias0 + c * 8);
    f32x4 b1 = *(const f32x4*)(bias0 + c * 8 + 4);
    const float inv9 = 1.f / 9.f;
    u32x4 out;
    #pragma unroll
    for (int k = 0; k < 4; ++k) {
        float a0 = 0.f, a1 = 0.f;
        #pragma unroll
        for (int j = 0; j < 9; ++j) {
            a0 += bf2f((unsigned short)v[j][k]);
            a1 += bf2f((unsigned short)(v[j][k] >> 16));
        }
        float bb0 = (k < 2) ? ((k == 0) ? b0.x : b0.z) : ((k == 2) ? b1.x : b1.z);
        float bb1 = (k < 2) ? ((k == 0) ? b0.y : b0.w) : ((k == 2) ? b1.y : b1.w);
        a0 = actf(a0 * inv9 + nz + bb0);
        a1 = actf(a1 * inv9 + nz + bb1);
        out[k] = packbf(a0, a1);
    }
    *(u32x4*)(h1u + (size_t)f * 64 + c * 4) = out;
}

// ---------------- FUSED gemm1 + gather1 + act + rgb dot, LDS weights ----------
// One wave = 16 faces x 96 output channels. t=1,2 slices (48 KB) in LDS.
__launch_bounds__(256, 2)
__global__ void k_fgemm1(const unsigned short* __restrict__ h1,
                         const unsigned short* __restrict__ wm,
                         const int* __restrict__ fn1,
                         const unsigned* __restrict__ zrow,
                         const float* __restrict__ nco1, const float* __restrict__ ns1p,
                         const float* __restrict__ bias1, const float* __restrict__ wrgbmod,
                         float* __restrict__ hout, f32x4* __restrict__ rgb3)
{
    __shared__ char ldsw[49152];  // rows 0..191 = t=1,2 slices, 256 B/row, swizzled
    int bid = xcd_swz(blockIdx.x, gridDim.x);
    int lane = threadIdx.x & 63;
    int w = threadIdx.x >> 6;
    int fbase = (bid * 4 + w) * 16;
    int quad = lane >> 4, l15 = lane & 15;
    int face = fbase + l15;
    const char* hb = (const char*)h1;
    const char* wb = (const char*)wm;

    // stage wm rows 96..287 (t=1,2)
    #pragma unroll
    for (int i0 = 0; i0 < 12; ++i0) {
        int i = i0 * 256 + threadIdx.x;
        u32x4 v = *(const u32x4*)(wb + 24576 + (size_t)i * 16);
        int r = i >> 4, c = i & 15;
        *(u32x4*)(ldsw + r * 256 + ((c ^ (r & 7)) * 16)) = v;
    }
    __syncthreads();

    int id[9];
    #pragma unroll
    for (int j = 0; j < 9; ++j) id[j] = fn1[(size_t)face * 9 + j];

    f32x4 ymax[6];
    #pragma unroll
    for (int mt = 0; mt < 6; ++mt)
        #pragma unroll
        for (int r = 0; r < 4; ++r) ymax[mt][r] = -3.0e38f;

    int xr = l15 & 7;

    #pragma unroll
    for (int j = 0; j < 9; ++j) {
        const int t = (j == 0) ? 0 : ((j < 5) ? 1 : 2);
        const char* src = ((unsigned)id[j] < FF) ? (hb + (size_t)id[j] * 256) : (const char*)zrow;
        bf16x8 bfr[4];
        #pragma unroll
        for (int s = 0; s < 4; ++s)
            bfr[s] = *(const bf16x8*)(src + s * 64 + quad * 16);
        f32x4 acc[6];
        #pragma unroll
        for (int mt = 0; mt < 6; ++mt)
            #pragma unroll
            for (int r = 0; r < 4; ++r) acc[mt][r] = 0.f;
        #pragma unroll
        for (int s = 0; s < 4; ++s) {
            #pragma unroll
            for (int mt = 0; mt < 6; ++mt) {
                bf16x8 afr;
                if (t == 0)
                    afr = *(const bf16x8*)(wb + (size_t)(((mt * 16 + l15) * 128 + s * 32 + quad * 8) * 2));
                else
                    afr = *(const bf16x8*)(ldsw + ((t - 1) * 96 + mt * 16 + l15) * 256
                                                + (((s * 4 + quad) ^ xr) * 16));
                acc[mt] = __builtin_amdgcn_mfma_f32_16x16x32_bf16(afr, bfr[s], acc[mt], 0, 0, 0);
            }
        }
        #pragma unroll
        for (int mt = 0; mt < 6; ++mt)
            #pragma unroll
            for (int r = 0; r < 4; ++r)
                ymax[mt][r] = fmaxf(ymax[mt][r], acc[mt][r]);
    }

    float ns1 = ns1p[0];
    float nz = nco1[face] * ns1;
    float p0 = 0.f, p1 = 0.f, p2 = 0.f;
    #pragma unroll
    for (int mt = 0; mt < 6; ++mt) {
        f32x4 bv = *(const f32x4*)(bias1 + mt * 16 + quad * 4);
        f32x4 hv;
        #pragma unroll
        for (int r = 0; r < 4; ++r) hv[r] = actf(ymax[mt][r] + nz + bv[r]);
        __builtin_nontemporal_store(hv, (f32x4*)(hout + (size_t)face * 96 + mt * 16 + quad * 4));
        f32x4 w0 = *(const f32x4*)(wrgbmod + mt * 16 + quad * 4);
        f32x4 w1 = *(const f32x4*)(wrgbmod + 96 + mt * 16 + quad * 4);
        f32x4 w2 = *(const f32x4*)(wrgbmod + 192 + mt * 16 + quad * 4);
        p0 += hv.x * w0.x + hv.y * w0.y + hv.z * w0.z + hv.w * w0.w;
        p1 += hv.x * w1.x + hv.y * w1.y + hv.z * w1.z + hv.w * w1.w;
        p2 += hv.x * w2.x + hv.y * w2.y + hv.z * w2.z + hv.w * w2.w;
    }
    p0 += __shfl_xor(p0, 16, 64); p0 += __shfl_xor(p0, 32, 64);
    p1 += __shfl_xor(p1, 16, 64); p1 += __shfl_xor(p1, 32, 64);
    p2 += __shfl_xor(p2, 16, 64); p2 += __shfl_xor(p2, 32, 64);
    if (quad == 0) {
        f32x4 o; o.x = p0; o.y = p1; o.z = p2; o.w = 0.f;
        rgb3[face] = o;
    }
}

// ---------------- torgb final: img_out = mean9(img[cidx]) + clamp(rgb3[g0]+b) ----------------
__global__ void k_torgb2(const f32x4* __restrict__ rgb3, const int* __restrict__ fn1,
                         const int* __restrict__ cidx, const float* __restrict__ img,
                         const float* __restrict__ brgb, float* __restrict__ imgout)
{
    int f = blockIdx.x * 256 + threadIdx.x;
    int g0 = fn1[(size_t)f * 9];
    float y0 = 0.f, y1 = 0.f, y2 = 0.f;
    if ((unsigned)g0 < FF) {
        f32x4 y = rgb3[g0];
        y0 = y.x; y1 = y.y; y2 = y.z;
    }
    y0 = fminf(fmaxf(y0 + brgb[0], -CLAMP_V), CLAMP_V);
    y1 = fminf(fmaxf(y1 + brgb[1], -CLAMP_V), CLAMP_V);
    y2 = fminf(fmaxf(y2 + brgb[2], -CLAMP_V), CLAMP_V);
    float i0 = 0.f, i1 = 0.f, i2 = 0.f;
    #pragma unroll
    for (int j = 0; j < 9; ++j) {
        int id = cidx[f * 9 + j];
        if (id >= 0) {
            const float* ir = img + (size_t)id * 3;
            i0 += ir[0]; i1 += ir[1]; i2 += ir[2];
        }
    }
    const float inv9 = 1.f / 9.f;
    imgout[(size_t)f * 3 + 0] = i0 * inv9 + y0;
    imgout[(size_t)f * 3 + 1] = i1 * inv9 + y1;
    imgout[(size_t)f * 3 + 2] = i2 * inv9 + y2;
}

extern "C" void kernel_launch(void* const* d_in, const int* in_sizes, int n_in,
                              void* d_out, int out_size, void* d_ws, size_t ws_size,
                              hipStream_t stream) {
    const float* x     = (const float*)d_in[0];
    const float* sfeat = (const float*)d_in[1];
    const float* img   = (const float*)d_in[2];
    const float* wsv   = (const float*)d_in[3];
    const int* fn0     = (const int*)d_in[4];
    const int* fn1     = (const int*)d_in[5];
    const int* pmap    = (const int*)d_in[6];
    const float* a0w   = (const float*)d_in[9];
    const float* a0b   = (const float*)d_in[10];
    const float* wc0   = (const float*)d_in[11];
    const float* wsd0  = (const float*)d_in[12];
    const float* wcr0  = (const float*)d_in[13];
    const float* ns0   = (const float*)d_in[14];
    const float* bias0 = (const float*)d_in[15];
    const float* nco0  = (const float*)d_in[16];
    const float* a1w   = (const float*)d_in[17];
    const float* a1b   = (const float*)d_in[18];
    const float* wc1   = (const float*)d_in[19];
    const float* wsd1  = (const float*)d_in[20];
    const float* wcr1  = (const float*)d_in[21];
    const float* ns1   = (const float*)d_in[22];
    const float* bias1 = (const float*)d_in[23];
    const float* nco1  = (const float*)d_in[24];
    const float* a2w   = (const float*)d_in[25];
    const float* a2b   = (const float*)d_in[26];
    const float* wrgb  = (const float*)d_in[27];
    const float* brgb  = (const float*)d_in[28];

    char* wsb = (char*)d_ws;
    float* s0            = (float*)(wsb + 0);
    float* s1            = (float*)(wsb + 512);
    float* s2            = (float*)(wsb + 1024);
    float* wrgbmod       = (float*)(wsb + 1536);
    unsigned* zrow       = (unsigned*)(wsb + 4096);
    unsigned short* wm0  = (unsigned short*)(wsb + 8192);
    unsigned short* wm1  = (unsigned short*)(wsb + 8192 + 98304);
    unsigned short* xcat = (unsigned short*)(wsb + 262144);      // 8.39 MB
    unsigned* hc0        = (unsigned*)(wsb + 33816576);          // 8.39 MB
    unsigned short* h1   = (unsigned short*)(wsb + 42205184);    // 33.55 MB
    int* cidx            = (int*)(wsb + 75759616);               // 4.72 MB
    f32x4* rgb3          = (f32x4*)(wsb + 155975680);            // 2.10 MB

    float* out_h   = (float*)d_out;
    float* out_img = out_h + (size_t)FF * 96;

    k_misc<<<FC * 32 / 256 + FF * 9 / 256, 256, 0, stream>>>(x, sfeat, (u16x4*)xcat, fn1, pmap, cidx);
    k_prep2<<<89, 256, 0, stream>>>(wsv, a0w, a0b, a1w, a1b, a2w, a2b, s0, s1, s2, zrow);
    k_wmod<<<225, 128, 0, stream>>>(wc0, wsd0, wcr0, s0, wm0,
                                    wc1, wsd1, wcr1, s1, wm1, wrgb, s2, wrgbmod);
    k_fgemm0<<<FC / 32, 256, 0, stream>>>(xcat, wm0, fn0, zrow, hc0);
    k_upsample<<<FF * 16 / 256, 256, 0, stream>>>(hc0, cidx, nco0, ns0, bias0, (unsigned*)h1, zrow);
    k_fgemm1<<<FF / 64, 256, 0, stream>>>(h1, wm1, fn1, zrow, nco1, ns1, bias1, wrgbmod,
                                          out_h, rgb3);
    k_torgb2<<<FF / 256, 256, 0, stream>>>(rgb3, fn1, cidx, img, brgb, out_img);
}

// Round 6
// 282.968 us; speedup vs baseline: 2.1352x; 1.0165x over previous
//
#include <hip/hip_runtime.h>

#define FC 32768
#define FF 131072
#define LRELU_SLOPE 0.2f
#define ACT_GAIN 1.4142135623730951f
#define CLAMP_V 256.0f

typedef __bf16 bf16x8 __attribute__((ext_vector_type(8)));
typedef float f32x4 __attribute__((ext_vector_type(4)));
typedef float f32x2 __attribute__((ext_vector_type(2)));
typedef unsigned u32x4 __attribute__((ext_vector_type(4)));
typedef unsigned u32x2 __attribute__((ext_vector_type(2)));
typedef unsigned short u16x4 __attribute__((ext_vector_type(4)));

static __device__ __forceinline__ unsigned short f2bf(float f) {
    unsigned u = __float_as_uint(f);
    u += 0x7FFFu + ((u >> 16) & 1u);
    return (unsigned short)(u >> 16);
}
static __device__ __forceinline__ unsigned packbf(float a, float b) {
    return (unsigned)f2bf(a) | ((unsigned)f2bf(b) << 16);
}
static __device__ __forceinline__ float bf2f(unsigned short u) {
    return __uint_as_float(((unsigned)u) << 16);
}
static __device__ __forceinline__ float actf(float v) {
    v = (v < 0.f) ? v * LRELU_SLOPE : v;
    v *= ACT_GAIN;
    return fminf(fmaxf(v, -CLAMP_V), CLAMP_V);
}
// XCD-aware chunked swizzle; valid when nwg % 8 == 0 (all our grids are).
static __device__ __forceinline__ int xcd_swz(int bid, int nwg) {
    return (bid & 7) * (nwg >> 3) + (bid >> 3);
}

// ---------------- styles: wave-per-output affine + zrow init ----------------
__global__ void k_prep2(const float* __restrict__ wsvec,
                        const float* __restrict__ a0w, const float* __restrict__ a0b,
                        const float* __restrict__ a1w, const float* __restrict__ a1b,
                        const float* __restrict__ a2w, const float* __restrict__ a2b,
                        float* __restrict__ s0, float* __restrict__ s1, float* __restrict__ s2,
                        unsigned* __restrict__ zrow)
{
    int lane = threadIdx.x & 63;
    int t = blockIdx.x * 4 + (threadIdx.x >> 6);
    if (t >= 352) {
        if (t == 352) zrow[lane] = 0u;
        return;
    }
    int level, o;
    const float *W, *bptr; float* out;
    if (t < 128)       { level = 0; o = t;       W = a0w; bptr = a0b; out = s0; }
    else if (t < 256)  { level = 1; o = t - 128; W = a1w; bptr = a1b; out = s1; }
    else               { level = 2; o = t - 256; W = a2w; bptr = a2b; out = s2; }
    const float* wrow = wsvec + level * 512;
    const float* Wr = W + (size_t)o * 512;
    f32x4 wa = *(const f32x4*)(wrow + lane * 8);
    f32x4 wb = *(const f32x4*)(wrow + lane * 8 + 4);
    f32x4 va = *(const f32x4*)(Wr + lane * 8);
    f32x4 vb = *(const f32x4*)(Wr + lane * 8 + 4);
    float acc = wa.x * va.x + wa.y * va.y + wa.z * va.z + wa.w * va.w
              + wb.x * vb.x + wb.y * vb.y + wb.z * vb.z + wb.w * vb.w;
    #pragma unroll
    for (int off = 32; off; off >>= 1) acc += __shfl_down(acc, off, 64);
    if (lane == 0) {
        float v = acc * 0.04419417382415922f + bptr[o];
        if (level == 2) v *= 0.10206207261596577f;  // 1/sqrt(96) torgb weight gain
        out[o] = v;
    }
}

// ---------------- fused: cvt (concat->bf16) + composed index ----------------
__global__ void k_misc(const float* __restrict__ x, const float* __restrict__ sf,
                       u16x4* __restrict__ xcat,
                       const int* __restrict__ fn1, const int* __restrict__ pmap,
                       int* __restrict__ cidx)
{
    int b = blockIdx.x;
    if (b < FC * 32 / 256) {
        int gid = b * 256 + threadIdx.x;
        int f = gid >> 5;
        int c4 = (gid & 31) * 4;
        f32x4 v;
        if (c4 < 96) v = *(const f32x4*)(x + (size_t)f * 96 + c4);
        else         v = *(const f32x4*)(sf + (size_t)f * 32 + (c4 - 96));
        u16x4 o;
        o.x = f2bf(v.x); o.y = f2bf(v.y); o.z = f2bf(v.z); o.w = f2bf(v.w);
        xcat[gid] = o;
    } else {
        int gid = (b - FC * 32 / 256) * 256 + threadIdx.x;  // FF*9
        int g = fn1[gid];
        cidx[gid] = ((unsigned)g < FF) ? pmap[g] : -1;
    }
}

// ---------------- fused weight prep ----------------
__global__ void k_wmod(const float* __restrict__ wc0, const float* __restrict__ wsd0,
                       const float* __restrict__ wcr0, const float* __restrict__ s0,
                       unsigned short* __restrict__ wm0,
                       const float* __restrict__ wc1, const float* __restrict__ wsd1,
                       const float* __restrict__ wcr1, const float* __restrict__ s1,
                       unsigned short* __restrict__ wm1,
                       const float* __restrict__ wrgb, const float* __restrict__ s2,
                       float* __restrict__ wrgbmod)
{
    int b = blockIdx.x;
    int i = threadIdx.x;  // 128
    if (b == 224) {
        for (int t = i; t < 288; t += 128) {
            int c = t / 96, k = t % 96;
            wrgbmod[c * 96 + k] = wrgb[c * 96 + k] * s2[k];
        }
        return;
    }
    const float *wc, *wsd, *wcr, *s; unsigned short* out; int o, O;
    if (b < 128) { wc = wc0; wsd = wsd0; wcr = wcr0; s = s0; out = wm0; o = b; O = 128; }
    else         { wc = wc1; wsd = wsd1; wcr = wcr1; s = s1; out = wm1; o = b - 128; O = 96; }
    float sv = s[i];
    float pc = wc[o * 128 + i] * sv;
    float ps = wsd[o * 128 + i] * sv;
    float pr = wcr[o * 128 + i] * sv;
    float part = pc * pc + 4.f * ps * ps + 4.f * pr * pr;
    __shared__ float red[2];
    #pragma unroll
    for (int off = 32; off; off >>= 1) part += __shfl_down(part, off, 64);
    if ((threadIdx.x & 63) == 0) red[threadIdx.x >> 6] = part;
    __syncthreads();
    float d = rsqrtf(red[0] + red[1] + 1e-8f);
    out[(0 * O + o) * 128 + i] = f2bf(pc * d);
    out[(1 * O + o) * 128 + i] = f2bf(ps * d);
    out[(2 * O + o) * 128 + i] = f2bf(pr * d);
}

// One j-step for fgemm0: gather one neighbor row, MFMA vs weight slice TT, fold max.
template<int TT>
static __device__ __forceinline__ void step0(int idv, const char* hb, const char* wb,
                                             const char* ldsw, const unsigned* zrow,
                                             int quad, int l15, int xr, f32x4 (&ymax)[8])
{
    const char* src = ((unsigned)idv < FC) ? (hb + (size_t)idv * 256) : (const char*)zrow;
    bf16x8 bfr[4];
    #pragma unroll
    for (int s = 0; s < 4; ++s)
        bfr[s] = *(const bf16x8*)(src + s * 64 + quad * 16);
    f32x4 acc[8];
    #pragma unroll
    for (int mt = 0; mt < 8; ++mt)
        #pragma unroll
        for (int r = 0; r < 4; ++r) acc[mt][r] = 0.f;
    #pragma unroll
    for (int s = 0; s < 4; ++s) {
        #pragma unroll
        for (int mt = 0; mt < 8; ++mt) {
            bf16x8 afr;
            if (TT == 0)
                afr = *(const bf16x8*)(wb + (size_t)(((mt * 16 + l15) * 128 + s * 32 + quad * 8) * 2));
            else
                afr = *(const bf16x8*)(ldsw + ((TT - 1) * 128 + mt * 16 + l15) * 256
                                            + (((s * 4 + quad) ^ xr) * 16));
            acc[mt] = __builtin_amdgcn_mfma_f32_16x16x32_bf16(afr, bfr[s], acc[mt], 0, 0, 0);
        }
    }
    #pragma unroll
    for (int mt = 0; mt < 8; ++mt)
        #pragma unroll
        for (int r = 0; r < 4; ++r)
            ymax[mt][r] = fmaxf(ymax[mt][r], acc[mt][r]);
}

// ---------------- FUSED gemm0 + gather0, LDS weights, j-split wave pairs ----
// Block: 4 waves = 2 face-groups x 2 j-halves. Wave (fgrp,wq): 16 faces x 128 ch,
// wq=0 -> j=0..3, wq=1 -> j=4..8. Partials combined via LDS max (aliases weight
// staging after a barrier). Serial gather chain per wave: 9 -> 4/5 rounds.
__launch_bounds__(256, 2)
__global__ void k_fgemm0(const unsigned short* __restrict__ xcat,
                         const unsigned short* __restrict__ wm,
                         const int* __restrict__ fn0,
                         const unsigned* __restrict__ zrow,
                         unsigned* __restrict__ hc0)
{
    __shared__ char ldsw[65536];  // rows 0..255 = t=1,2 slices, 256 B/row, swizzled
    int bid = xcd_swz(blockIdx.x, gridDim.x);
    int lane = threadIdx.x & 63;
    int w = threadIdx.x >> 6;
    int fgrp = w >> 1;
    int wq = w & 1;
    int fbase = (bid * 2 + fgrp) * 16;
    int quad = lane >> 4, l15 = lane & 15;
    int face = fbase + l15;
    const char* hb = (const char*)xcat;
    const char* wb = (const char*)wm;

    // stage wm rows 128..383 (t=1,2): chunk i -> row i>>4, col16 (i&15)^(row&7)
    #pragma unroll
    for (int i0 = 0; i0 < 16; ++i0) {
        int i = i0 * 256 + threadIdx.x;
        u32x4 v = *(const u32x4*)(wb + 32768 + (size_t)i * 16);
        int r = i >> 4, c = i & 15;
        *(u32x4*)(ldsw + r * 256 + ((c ^ (r & 7)) * 16)) = v;
    }
    __syncthreads();

    int id[5];
    #pragma unroll
    for (int k = 0; k < 5; ++k) {
        int jj = wq ? (4 + k) : ((k < 4) ? k : 4);
        id[k] = fn0[(size_t)face * 9 + jj];
    }

    f32x4 ymax[8];
    #pragma unroll
    for (int mt = 0; mt < 8; ++mt)
        #pragma unroll
        for (int r = 0; r < 4; ++r) ymax[mt][r] = -3.0e38f;

    int xr = l15 & 7;

    if (wq == 0) {  // j = 0 (center, t0) + 1..3 (sides, t1)
        step0<0>(id[0], hb, wb, ldsw, zrow, quad, l15, xr, ymax);
        step0<1>(id[1], hb, wb, ldsw, zrow, quad, l15, xr, ymax);
        step0<1>(id[2], hb, wb, ldsw, zrow, quad, l15, xr, ymax);
        step0<1>(id[3], hb, wb, ldsw, zrow, quad, l15, xr, ymax);
    } else {        // j = 4 (side, t1) + 5..8 (corners, t2)
        step0<1>(id[0], hb, wb, ldsw, zrow, quad, l15, xr, ymax);
        step0<2>(id[1], hb, wb, ldsw, zrow, quad, l15, xr, ymax);
        step0<2>(id[2], hb, wb, ldsw, zrow, quad, l15, xr, ymax);
        step0<2>(id[3], hb, wb, ldsw, zrow, quad, l15, xr, ymax);
        step0<2>(id[4], hb, wb, ldsw, zrow, quad, l15, xr, ymax);
    }

    // combine partial maxes via LDS (weights dead after this barrier)
    __syncthreads();
    float* cmb = (float*)ldsw;
    if (wq == 1) {
        #pragma unroll
        for (int mt = 0; mt < 8; ++mt)
            *(f32x4*)(cmb + (fgrp * 16 + l15) * 132 + mt * 16 + quad * 4) = ymax[mt];
    }
    __syncthreads();
    if (wq == 0) {
        #pragma unroll
        for (int mt = 0; mt < 8; ++mt) {
            f32x4 o = *(const f32x4*)(cmb + (fgrp * 16 + l15) * 132 + mt * 16 + quad * 4);
            #pragma unroll
            for (int r = 0; r < 4; ++r) ymax[mt][r] = fmaxf(ymax[mt][r], o[r]);
            u32x2 v;
            v.x = packbf(ymax[mt][0], ymax[mt][1]);
            v.y = packbf(ymax[mt][2], ymax[mt][3]);
            *(u32x2*)(hc0 + (size_t)face * 64 + mt * 8 + quad * 2) = v;
        }
    }
}

// ---------------- upsample + noise + act -> h1 bf16 [FF][128] ----------------
__global__ void k_upsample(const unsigned* __restrict__ hc, const int* __restrict__ cidx,
                           const float* __restrict__ nco0,
                           const float* __restrict__ ns0p, const float* __restrict__ bias0,
                           unsigned* __restrict__ h1u, const unsigned* __restrict__ zrow)
{
    int bid = xcd_swz(blockIdx.x, gridDim.x);
    int gid = bid * 256 + threadIdx.x;  // FF*16
    int f = gid >> 4;
    int c = gid & 15;
    int id[9];
    #pragma unroll
    for (int j = 0; j < 9; ++j) id[j] = cidx[f * 9 + j];
    u32x4 v[9];
    #pragma unroll
    for (int j = 0; j < 9; ++j) {
        const unsigned* p = (id[j] >= 0) ? (hc + (size_t)id[j] * 64) : zrow;
        v[j] = *(const u32x4*)(p + c * 4);
    }
    float nz = nco0[f] * ns0p[0];
    f32x4 b0 = *(const f32x4*)(bias0 + c * 8);
    f32x4 b1 = *(const f32x4*)(bias0 + c * 8 + 4);
    const float inv9 = 1.f / 9.f;
    u32x4 out;
    #pragma unroll
    for (int k = 0; k < 4; ++k) {
        float a0 = 0.f, a1 = 0.f;
        #pragma unroll
        for (int j = 0; j < 9; ++j) {
            a0 += bf2f((unsigned short)v[j][k]);
            a1 += bf2f((unsigned short)(v[j][k] >> 16));
        }
        float bb0 = (k < 2) ? ((k == 0) ? b0.x : b0.z) : ((k == 2) ? b1.x : b1.z);
        float bb1 = (k < 2) ? ((k == 0) ? b0.y : b0.w) : ((k == 2) ? b1.y : b1.w);
        a0 = actf(a0 * inv9 + nz + bb0);
        a1 = actf(a1 * inv9 + nz + bb1);
        out[k] = packbf(a0, a1);
    }
    *(u32x4*)(h1u + (size_t)f * 64 + c * 4) = out;
}

// One j-step for fgemm1.
template<int TT>
static __device__ __forceinline__ void step1(int idv, const char* hb, const char* wb,
                                             const char* ldsw, const unsigned* zrow,
                                             int quad, int l15, int xr, f32x4 (&ymax)[6])
{
    const char* src = ((unsigned)idv < FF) ? (hb + (size_t)idv * 256) : (const char*)zrow;
    bf16x8 bfr[4];
    #pragma unroll
    for (int s = 0; s < 4; ++s)
        bfr[s] = *(const bf16x8*)(src + s * 64 + quad * 16);
    f32x4 acc[6];
    #pragma unroll
    for (int mt = 0; mt < 6; ++mt)
        #pragma unroll
        for (int r = 0; r < 4; ++r) acc[mt][r] = 0.f;
    #pragma unroll
    for (int s = 0; s < 4; ++s) {
        #pragma unroll
        for (int mt = 0; mt < 6; ++mt) {
            bf16x8 afr;
            if (TT == 0)
                afr = *(const bf16x8*)(wb + (size_t)(((mt * 16 + l15) * 128 + s * 32 + quad * 8) * 2));
            else
                afr = *(const bf16x8*)(ldsw + ((TT - 1) * 96 + mt * 16 + l15) * 256
                                            + (((s * 4 + quad) ^ xr) * 16));
            acc[mt] = __builtin_amdgcn_mfma_f32_16x16x32_bf16(afr, bfr[s], acc[mt], 0, 0, 0);
        }
    }
    #pragma unroll
    for (int mt = 0; mt < 6; ++mt)
        #pragma unroll
        for (int r = 0; r < 4; ++r)
            ymax[mt][r] = fmaxf(ymax[mt][r], acc[mt][r]);
}

// ---------------- FUSED gemm1 + gather1 + act + rgb dot, j-split wave pairs ----
// Block: 4 waves = 2 face-groups x 2 j-halves; 32 faces/block, 96 ch/wave.
__launch_bounds__(256, 2)
__global__ void k_fgemm1(const unsigned short* __restrict__ h1,
                         const unsigned short* __restrict__ wm,
                         const int* __restrict__ fn1,
                         const unsigned* __restrict__ zrow,
                         const float* __restrict__ nco1, const float* __restrict__ ns1p,
                         const float* __restrict__ bias1, const float* __restrict__ wrgbmod,
                         float* __restrict__ hout, f32x4* __restrict__ rgb3)
{
    __shared__ char ldsw[49152];  // rows 0..191 = t=1,2 slices, 256 B/row, swizzled
    int bid = xcd_swz(blockIdx.x, gridDim.x);
    int lane = threadIdx.x & 63;
    int w = threadIdx.x >> 6;
    int fgrp = w >> 1;
    int wq = w & 1;
    int fbase = (bid * 2 + fgrp) * 16;
    int quad = lane >> 4, l15 = lane & 15;
    int face = fbase + l15;
    const char* hb = (const char*)h1;
    const char* wb = (const char*)wm;

    // stage wm rows 96..287 (t=1,2)
    #pragma unroll
    for (int i0 = 0; i0 < 12; ++i0) {
        int i = i0 * 256 + threadIdx.x;
        u32x4 v = *(const u32x4*)(wb + 24576 + (size_t)i * 16);
        int r = i >> 4, c = i & 15;
        *(u32x4*)(ldsw + r * 256 + ((c ^ (r & 7)) * 16)) = v;
    }
    __syncthreads();

    int id[5];
    #pragma unroll
    for (int k = 0; k < 5; ++k) {
        int jj = wq ? (4 + k) : ((k < 4) ? k : 4);
        id[k] = fn1[(size_t)face * 9 + jj];
    }

    f32x4 ymax[6];
    #pragma unroll
    for (int mt = 0; mt < 6; ++mt)
        #pragma unroll
        for (int r = 0; r < 4; ++r) ymax[mt][r] = -3.0e38f;

    int xr = l15 & 7;

    if (wq == 0) {  // j=0 (center, t0) + 1..3 (sides, t1)
        step1<0>(id[0], hb, wb, ldsw, zrow, quad, l15, xr, ymax);
        step1<1>(id[1], hb, wb, ldsw, zrow, quad, l15, xr, ymax);
        step1<1>(id[2], hb, wb, ldsw, zrow, quad, l15, xr, ymax);
        step1<1>(id[3], hb, wb, ldsw, zrow, quad, l15, xr, ymax);
    } else {        // j=4 (side, t1) + 5..8 (corners, t2)
        step1<1>(id[0], hb, wb, ldsw, zrow, quad, l15, xr, ymax);
        step1<2>(id[1], hb, wb, ldsw, zrow, quad, l15, xr, ymax);
        step1<2>(id[2], hb, wb, ldsw, zrow, quad, l15, xr, ymax);
        step1<2>(id[3], hb, wb, ldsw, zrow, quad, l15, xr, ymax);
        step1<2>(id[4], hb, wb, ldsw, zrow, quad, l15, xr, ymax);
    }

    __syncthreads();
    float* cmb = (float*)ldsw;
    if (wq == 1) {
        #pragma unroll
        for (int mt = 0; mt < 6; ++mt)
            *(f32x4*)(cmb + (fgrp * 16 + l15) * 100 + mt * 16 + quad * 4) = ymax[mt];
    }
    __syncthreads();
    if (wq == 0) {
        float ns1 = ns1p[0];
        float nz = nco1[face] * ns1;
        float p0 = 0.f, p1 = 0.f, p2 = 0.f;
        #pragma unroll
        for (int mt = 0; mt < 6; ++mt) {
            f32x4 o = *(const f32x4*)(cmb + (fgrp * 16 + l15) * 100 + mt * 16 + quad * 4);
            f32x4 bv = *(const f32x4*)(bias1 + mt * 16 + quad * 4);
            f32x4 hv;
            #pragma unroll
            for (int r = 0; r < 4; ++r)
                hv[r] = actf(fmaxf(ymax[mt][r], o[r]) + nz + bv[r]);
            __builtin_nontemporal_store(hv, (f32x4*)(hout + (size_t)face * 96 + mt * 16 + quad * 4));
            f32x4 w0 = *(const f32x4*)(wrgbmod + mt * 16 + quad * 4);
            f32x4 w1 = *(const f32x4*)(wrgbmod + 96 + mt * 16 + quad * 4);
            f32x4 w2 = *(const f32x4*)(wrgbmod + 192 + mt * 16 + quad * 4);
            p0 += hv.x * w0.x + hv.y * w0.y + hv.z * w0.z + hv.w * w0.w;
            p1 += hv.x * w1.x + hv.y * w1.y + hv.z * w1.z + hv.w * w1.w;
            p2 += hv.x * w2.x + hv.y * w2.y + hv.z * w2.z + hv.w * w2.w;
        }
        p0 += __shfl_xor(p0, 16, 64); p0 += __shfl_xor(p0, 32, 64);
        p1 += __shfl_xor(p1, 16, 64); p1 += __shfl_xor(p1, 32, 64);
        p2 += __shfl_xor(p2, 16, 64); p2 += __shfl_xor(p2, 32, 64);
        if (quad == 0) {
            f32x4 o; o.x = p0; o.y = p1; o.z = p2; o.w = 0.f;
            rgb3[face] = o;
        }
    }
}

// ---------------- torgb final: img_out = mean9(img[cidx]) + clamp(rgb3[g0]+b) ----------------
__global__ void k_torgb2(const f32x4* __restrict__ rgb3, const int* __restrict__ fn1,
                         const int* __restrict__ cidx, const float* __restrict__ img,
                         const float* __restrict__ brgb, float* __restrict__ imgout)
{
    int f = blockIdx.x * 256 + threadIdx.x;
    int g0 = fn1[(size_t)f * 9];
    float y0 = 0.f, y1 = 0.f, y2 = 0.f;
    if ((unsigned)g0 < FF) {
        f32x4 y = rgb3[g0];
        y0 = y.x; y1 = y.y; y2 = y.z;
    }
    y0 = fminf(fmaxf(y0 + brgb[0], -CLAMP_V), CLAMP_V);
    y1 = fminf(fmaxf(y1 + brgb[1], -CLAMP_V), CLAMP_V);
    y2 = fminf(fmaxf(y2 + brgb[2], -CLAMP_V), CLAMP_V);
    float i0 = 0.f, i1 = 0.f, i2 = 0.f;
    #pragma unroll
    for (int j = 0; j < 9; ++j) {
        int id = cidx[f * 9 + j];
        if (id >= 0) {
            const float* ir = img + (size_t)id * 3;
            i0 += ir[0]; i1 += ir[1]; i2 += ir[2];
        }
    }
    const float inv9 = 1.f / 9.f;
    imgout[(size_t)f * 3 + 0] = i0 * inv9 + y0;
    imgout[(size_t)f * 3 + 1] = i1 * inv9 + y1;
    imgout[(size_t)f * 3 + 2] = i2 * inv9 + y2;
}

extern "C" void kernel_launch(void* const* d_in, const int* in_sizes, int n_in,
                              void* d_out, int out_size, void* d_ws, size_t ws_size,
                              hipStream_t stream) {
    const float* x     = (const float*)d_in[0];
    const float* sfeat = (const float*)d_in[1];
    const float* img   = (const float*)d_in[2];
    const float* wsv   = (const float*)d_in[3];
    const int* fn0     = (const int*)d_in[4];
    const int* fn1     = (const int*)d_in[5];
    const int* pmap    = (const int*)d_in[6];
    const float* a0w   = (const float*)d_in[9];
    const float* a0b   = (const float*)d_in[10];
    const float* wc0   = (const float*)d_in[11];
    const float* wsd0  = (const float*)d_in[12];
    const float* wcr0  = (const float*)d_in[13];
    const float* ns0   = (const float*)d_in[14];
    const float* bias0 = (const float*)d_in[15];
    const float* nco0  = (const float*)d_in[16];
    const float* a1w   = (const float*)d_in[17];
    const float* a1b   = (const float*)d_in[18];
    const float* wc1   = (const float*)d_in[19];
    const float* wsd1  = (const float*)d_in[20];
    const float* wcr1  = (const float*)d_in[21];
    const float* ns1   = (const float*)d_in[22];
    const float* bias1 = (const float*)d_in[23];
    const float* nco1  = (const float*)d_in[24];
    const float* a2w   = (const float*)d_in[25];
    const float* a2b   = (const float*)d_in[26];
    const float* wrgb  = (const float*)d_in[27];
    const float* brgb  = (const float*)d_in[28];

    char* wsb = (char*)d_ws;
    float* s0            = (float*)(wsb + 0);
    float* s1            = (float*)(wsb + 512);
    float* s2            = (float*)(wsb + 1024);
    float* wrgbmod       = (float*)(wsb + 1536);
    unsigned* zrow       = (unsigned*)(wsb + 4096);
    unsigned short* wm0  = (unsigned short*)(wsb + 8192);
    unsigned short* wm1  = (unsigned short*)(wsb + 8192 + 98304);
    unsigned short* xcat = (unsigned short*)(wsb + 262144);      // 8.39 MB
    unsigned* hc0        = (unsigned*)(wsb + 33816576);          // 8.39 MB
    unsigned short* h1   = (unsigned short*)(wsb + 42205184);    // 33.55 MB
    int* cidx            = (int*)(wsb + 75759616);               // 4.72 MB
    f32x4* rgb3          = (f32x4*)(wsb + 155975680);            // 2.10 MB

    float* out_h   = (float*)d_out;
    float* out_img = out_h + (size_t)FF * 96;

    k_misc<<<FC * 32 / 256 + FF * 9 / 256, 256, 0, stream>>>(x, sfeat, (u16x4*)xcat, fn1, pmap, cidx);
    k_prep2<<<89, 256, 0, stream>>>(wsv, a0w, a0b, a1w, a1b, a2w, a2b, s0, s1, s2, zrow);
    k_wmod<<<225, 128, 0, stream>>>(wc0, wsd0, wcr0, s0, wm0,
                                    wc1, wsd1, wcr1, s1, wm1, wrgb, s2, wrgbmod);
    k_fgemm0<<<FC / 32, 256, 0, stream>>>(xcat, wm0, fn0, zrow, hc0);
    k_upsample<<<FF * 16 / 256, 256, 0, stream>>>(hc0, cidx, nco0, ns0, bias0, (unsigned*)h1, zrow);
    k_fgemm1<<<FF / 32, 256, 0, stream>>>(h1, wm1, fn1, zrow, nco1, ns1, bias1, wrgbmod,
                                          out_h, rgb3);
    k_torgb2<<<FF / 256, 256, 0, stream>>>(rgb3, fn1, cidx, img, brgb, out_img);
}